// Round 3
// baseline (8432.696 us; speedup 1.0000x reference)
//
#include <hip/hip_runtime.h>
#include <hip/hip_cooperative_groups.h>
#include <math.h>

namespace cg = cooperative_groups;

// Problem dims: x (2,1,160,160,16) f32, lambda (2,3,160,160,16) f32, 48 iters.
#define XDIM 160
#define YDIM 160
#define TDIM 16
#define NB 2
#define T_ITERS 48

constexpr int VOL     = XDIM * YDIM * TDIM;   // 409600
constexpr int NX      = NB * VOL;             // 819200
constexpr int NQ      = NB * 3 * VOL;         // 2457600
constexpr int NQUAD   = NX / 4;               // 204800 threads (4 T-elems each)
constexpr int NBLOCKS = NQUAD / 256;          // 800 blocks -> needs 4 blocks/CU

__device__ __forceinline__ float clampl(float v, float l) {
    return fminf(fmaxf(v, -l), l);
}

// ============================ cooperative path ============================
// Persistent primal-dual solver. One launch; grid.sync() between iterations.
// Register-resident per thread (4 contiguous T elems): p, x0, xn, xbar_c,
// q0_c, q1_c, q2_c, lam0_c, lam1_c, lam2_c, lam0[xm], lam1[ym].
// Global (double-buffered) only what neighbors need: xbar, q0, q1.
// T-direction neighbors (q2, xbar t+/-1) via __shfl within 4-lane groups.
__global__ __launch_bounds__(256, 4) void pd_persistent(
    const float* __restrict__ x, const float* __restrict__ lam,
    float* __restrict__ out,
    float* __restrict__ xbA, float* __restrict__ xbB,
    float* __restrict__ q0A, float* __restrict__ q0B,
    float* __restrict__ q1A, float* __restrict__ q1B,
    float sigma, float inv1ps, float tau, float theta)
{
    cg::grid_group grid = cg::this_grid();
    const int tid = blockIdx.x * blockDim.x + threadIdx.x;  // 0..NQUAD-1

    const int t0    = (tid & 3) * 4;       // 0,4,8,12
    const int rest  = tid >> 2;            // line index: b*X*Y + xx*Y + yy
    const int yy    = rest % YDIM;
    const int rest2 = rest / YDIM;
    const int xx    = rest2 % XDIM;
    const int b     = rest2 / XDIM;

    const int xp = (xx == XDIM - 1) ? 0 : xx + 1;
    const int xm = (xx == 0) ? XDIM - 1 : xx - 1;
    const int yp = (yy == YDIM - 1) ? 0 : yy + 1;
    const int ym = (yy == 0) ? YDIM - 1 : yy - 1;

    const int xbase = b * VOL;
    const int off   = xbase + (xx * YDIM + yy) * TDIM + t0;
    const int offXP = xbase + (xp * YDIM + yy) * TDIM + t0;
    const int offXM = xbase + (xm * YDIM + yy) * TDIM + t0;
    const int offYP = xbase + (xx * YDIM + yp) * TDIM + t0;
    const int offYM = xbase + (xx * YDIM + ym) * TDIM + t0;

    const int lbase   = b * 3 * VOL;
    const int l0off   = lbase + (xx * YDIM + yy) * TDIM + t0;
    const int l0offXM = lbase + (xm * YDIM + yy) * TDIM + t0;
    const int l1offYM = lbase + VOL + (xx * YDIM + ym) * TDIM + t0;

    const int lane  = threadIdx.x & 63;
    const int upSrc = (lane & 60) | (((lane & 3) + 1) & 3);  // quad t0+4 (wraps)
    const int dnSrc = (lane & 60) | (((lane & 3) + 3) & 3);  // quad t0-4 (wraps)

    const float4 vC  = *(const float4*)(x + off);
    const float4 L0  = *(const float4*)(lam + l0off);
    const float4 L1  = *(const float4*)(lam + l0off + VOL);
    const float4 L2  = *(const float4*)(lam + l0off + 2 * VOL);
    const float4 L0M = *(const float4*)(lam + l0offXM);
    const float4 L1M = *(const float4*)(lam + l1offYM);

    float xnc[4] = {vC.x, vC.y, vC.z, vC.w};
    float pc[4]  = {vC.x, vC.y, vC.z, vC.w};
    float x0c[4] = {vC.x, vC.y, vC.z, vC.w};
    float xbc[4] = {vC.x, vC.y, vC.z, vC.w};
    float q0c[4] = {0.f, 0.f, 0.f, 0.f};
    float q1c[4] = {0.f, 0.f, 0.f, 0.f};
    float q2c[4] = {0.f, 0.f, 0.f, 0.f};
    float l0c[4] = {L0.x, L0.y, L0.z, L0.w};
    float l1c[4] = {L1.x, L1.y, L1.z, L1.w};
    float l2c[4] = {L2.x, L2.y, L2.z, L2.w};
    float l0m[4] = {L0M.x, L0M.y, L0M.z, L0M.w};
    float l1m[4] = {L1M.x, L1M.y, L1M.z, L1M.w};
    const float l2p = __shfl(l2c[3], dnSrc, 64);

    *(float4*)(xbA + off) = vC;
    *(float4*)(q0A + off) = make_float4(0.f, 0.f, 0.f, 0.f);
    *(float4*)(q1A + off) = make_float4(0.f, 0.f, 0.f, 0.f);

    for (int it = 0; it < T_ITERS; ++it) {
        __threadfence();
        grid.sync();

        const float* xbi = (it & 1) ? xbB : xbA;
        const float* q0i = (it & 1) ? q0B : q0A;
        const float* q1i = (it & 1) ? q1B : q1A;
        float* xbo = (it & 1) ? xbA : xbB;
        float* q0o = (it & 1) ? q0A : q0B;
        float* q1o = (it & 1) ? q1A : q1B;

        const float4 XP  = *(const float4*)(xbi + offXP);
        const float4 XM  = *(const float4*)(xbi + offXM);
        const float4 YP  = *(const float4*)(xbi + offYP);
        const float4 YM  = *(const float4*)(xbi + offYM);
        const float4 Q0M = *(const float4*)(q0i + offXM);
        const float4 Q1M = *(const float4*)(q1i + offYM);

        float xbxp[4] = {XP.x, XP.y, XP.z, XP.w};
        float xbxm[4] = {XM.x, XM.y, XM.z, XM.w};
        float xbyp[4] = {YP.x, YP.y, YP.z, YP.w};
        float xbym[4] = {YM.x, YM.y, YM.z, YM.w};
        float q0xm[4] = {Q0M.x, Q0M.y, Q0M.z, Q0M.w};
        float q1ym[4] = {Q1M.x, Q1M.y, Q1M.z, Q1M.w};

        const float xb_tp = __shfl(xbc[0], upSrc, 64);
        const float xb_tm = __shfl(xbc[3], dnSrc, 64);
        const float q2_tm = __shfl(q2c[3], dnSrc, 64);

        float pn[4], q0n[4], q1n[4], q2n[4], x1v[4], xbn[4];

        #pragma unroll
        for (int j = 0; j < 4; ++j) {
            pn[j] = (pc[j] + sigma * (xbc[j] - xnc[j])) * inv1ps;

            float gx = xbxp[j] - xbc[j];
            float gy = xbyp[j] - xbc[j];
            float gt = ((j < 3) ? xbc[j + 1] : xb_tp) - xbc[j];

            q0n[j] = clampl(q0c[j] + sigma * gx, l0c[j]);
            q1n[j] = clampl(q1c[j] + sigma * gy, l1c[j]);
            q2n[j] = clampl(q2c[j] + sigma * gt, l2c[j]);

            float q0m = clampl(q0xm[j] + sigma * (xbc[j] - xbxm[j]), l0m[j]);
            float q1m = clampl(q1ym[j] + sigma * (xbc[j] - xbym[j]), l1m[j]);
            float gtm    = xbc[j] - ((j == 0) ? xb_tm : xbc[j - 1]);
            float q2prev = (j == 0) ? q2_tm : q2c[j - 1];
            float l2prev = (j == 0) ? l2p  : l2c[j - 1];
            float q2m = clampl(q2prev + sigma * gtm, l2prev);

            float div = (q0m - q0n[j]) + (q1m - q1n[j]) + (q2m - q2n[j]);

            x1v[j] = x0c[j] - tau * (pn[j] + div);
            xbn[j] = x1v[j] + theta * (x1v[j] - x0c[j]);
        }

        #pragma unroll
        for (int j = 0; j < 4; ++j) {
            pc[j]  = pn[j];
            q0c[j] = q0n[j];
            q1c[j] = q1n[j];
            q2c[j] = q2n[j];
            x0c[j] = x1v[j];
            xbc[j] = xbn[j];
        }

        if (it < T_ITERS - 1) {
            *(float4*)(xbo + off) = make_float4(xbn[0], xbn[1], xbn[2], xbn[3]);
            *(float4*)(q0o + off) = make_float4(q0n[0], q0n[1], q0n[2], q0n[3]);
            *(float4*)(q1o + off) = make_float4(q1n[0], q1n[1], q1n[2], q1n[3]);
        }
    }

    *(float4*)(out + off) = make_float4(x0c[0], x0c[1], x0c[2], x0c[3]);
}

// ============================ fallback path (proven R0) ============================
__global__ __launch_bounds__(256) void init_kernel(
    const float* __restrict__ x, float* __restrict__ xbuf, float* __restrict__ p,
    float* __restrict__ xbarA, float* __restrict__ qA)
{
    int i = blockIdx.x * blockDim.x + threadIdx.x;
    if (i < NX) {
        float v = x[i];
        xbuf[i]  = v;
        p[i]     = v;
        xbarA[i] = v;
    }
    if (i < NQ) qA[i] = 0.0f;
}

__global__ __launch_bounds__(256) void step_kernel(
    const float* __restrict__ xn,
    float* __restrict__ p,
    const float* __restrict__ qin, float* __restrict__ qout,
    const float* __restrict__ x0buf, float* __restrict__ x1out,
    const float* __restrict__ xbin, float* __restrict__ xbout,
    const float* __restrict__ lam,
    float sigma, float inv1ps, float tau, float theta)
{
    int tid = blockIdx.x * blockDim.x + threadIdx.x;
    if (tid >= NX / 4) return;

    const int t0    = (tid & 3) * 4;
    const int rest  = tid >> 2;
    const int yy    = rest % YDIM;
    const int rest2 = rest / YDIM;
    const int xx    = rest2 % XDIM;
    const int b     = rest2 / XDIM;

    const int xp = (xx == XDIM - 1) ? 0 : xx + 1;
    const int xm = (xx == 0) ? XDIM - 1 : xx - 1;
    const int yp = (yy == YDIM - 1) ? 0 : yy + 1;
    const int ym = (yy == 0) ? YDIM - 1 : yy - 1;

    const int sp    = xx * YDIM + yy;
    const int sp_xp = xp * YDIM + yy;
    const int sp_xm = xm * YDIM + yy;
    const int sp_yp = xx * YDIM + yp;
    const int sp_ym = xx * YDIM + ym;

    const int xbase = b * VOL;
    const int qbase = b * 3 * VOL;

    const int off    = xbase + sp * TDIM + t0;
    const int lineof = xbase + sp * TDIM;

    const float4 xbC  = *(const float4*)(xbin + off);
    const float4 xbXP = *(const float4*)(xbin + xbase + sp_xp * TDIM + t0);
    const float4 xbXM = *(const float4*)(xbin + xbase + sp_xm * TDIM + t0);
    const float4 xbYP = *(const float4*)(xbin + xbase + sp_yp * TDIM + t0);
    const float4 xbYM = *(const float4*)(xbin + xbase + sp_ym * TDIM + t0);
    const float xb_tm = xbin[lineof + ((t0 + TDIM - 1) & (TDIM - 1))];
    const float xb_tp = xbin[lineof + ((t0 + 4) & (TDIM - 1))];

    const float4 xnC = *(const float4*)(xn    + off);
    const float4 pC  = *(const float4*)(p     + off);
    const float4 x0C = *(const float4*)(x0buf + off);

    const int q0o = qbase + sp * TDIM + t0;
    const float4 q0C  = *(const float4*)(qin + q0o);
    const float4 q0XM = *(const float4*)(qin + qbase + sp_xm * TDIM + t0);
    const float4 q1C  = *(const float4*)(qin + q0o + VOL);
    const float4 q1YM = *(const float4*)(qin + qbase + VOL + sp_ym * TDIM + t0);
    const float4 q2C  = *(const float4*)(qin + q0o + 2 * VOL);
    const float  q2TM = qin[qbase + 2 * VOL + sp * TDIM + ((t0 + TDIM - 1) & (TDIM - 1))];

    const float4 l0C  = *(const float4*)(lam + q0o);
    const float4 l0XM = *(const float4*)(lam + qbase + sp_xm * TDIM + t0);
    const float4 l1C  = *(const float4*)(lam + q0o + VOL);
    const float4 l1YM = *(const float4*)(lam + qbase + VOL + sp_ym * TDIM + t0);
    const float4 l2C  = *(const float4*)(lam + q0o + 2 * VOL);
    const float  l2TM = lam[qbase + 2 * VOL + sp * TDIM + ((t0 + TDIM - 1) & (TDIM - 1))];

    float xbc[4]  = {xbC.x, xbC.y, xbC.z, xbC.w};
    float xbxp[4] = {xbXP.x, xbXP.y, xbXP.z, xbXP.w};
    float xbxm[4] = {xbXM.x, xbXM.y, xbXM.z, xbXM.w};
    float xbyp[4] = {xbYP.x, xbYP.y, xbYP.z, xbYP.w};
    float xbym[4] = {xbYM.x, xbYM.y, xbYM.z, xbYM.w};
    float xnc[4]  = {xnC.x, xnC.y, xnC.z, xnC.w};
    float pc[4]   = {pC.x, pC.y, pC.z, pC.w};
    float x0c[4]  = {x0C.x, x0C.y, x0C.z, x0C.w};
    float q0c[4]  = {q0C.x, q0C.y, q0C.z, q0C.w};
    float q0xm[4] = {q0XM.x, q0XM.y, q0XM.z, q0XM.w};
    float q1c[4]  = {q1C.x, q1C.y, q1C.z, q1C.w};
    float q1ym[4] = {q1YM.x, q1YM.y, q1YM.z, q1YM.w};
    float q2c[4]  = {q2C.x, q2C.y, q2C.z, q2C.w};
    float l0c[4]  = {l0C.x, l0C.y, l0C.z, l0C.w};
    float l0xm[4] = {l0XM.x, l0XM.y, l0XM.z, l0XM.w};
    float l1c[4]  = {l1C.x, l1C.y, l1C.z, l1C.w};
    float l1ym[4] = {l1YM.x, l1YM.y, l1YM.z, l1YM.w};
    float l2c[4]  = {l2C.x, l2C.y, l2C.z, l2C.w};

    float pn[4], q0n[4], q1n[4], q2n[4], x1v[4], xbn[4];

    #pragma unroll
    for (int j = 0; j < 4; ++j) {
        pn[j] = (pc[j] + sigma * (xbc[j] - xnc[j])) * inv1ps;

        float gx = xbxp[j] - xbc[j];
        float gy = xbyp[j] - xbc[j];
        float gt = ((j < 3) ? xbc[j + 1] : xb_tp) - xbc[j];

        q0n[j] = clampl(q0c[j] + sigma * gx, l0c[j]);
        q1n[j] = clampl(q1c[j] + sigma * gy, l1c[j]);
        q2n[j] = clampl(q2c[j] + sigma * gt, l2c[j]);

        float q0m = clampl(q0xm[j] + sigma * (xbc[j] - xbxm[j]), l0xm[j]);
        float q1m = clampl(q1ym[j] + sigma * (xbc[j] - xbym[j]), l1ym[j]);
        float gtm  = xbc[j] - ((j == 0) ? xb_tm : xbc[j - 1]);
        float q2prev = (j == 0) ? q2TM : q2c[j - 1];
        float l2prev = (j == 0) ? l2TM : l2c[j - 1];
        float q2m = clampl(q2prev + sigma * gtm, l2prev);

        float div = (q0m - q0n[j]) + (q1m - q1n[j]) + (q2m - q2n[j]);

        x1v[j] = x0c[j] - tau * (pn[j] + div);
        xbn[j] = x1v[j] + theta * (x1v[j] - x0c[j]);
    }

    *(float4*)(p + off)            = make_float4(pn[0], pn[1], pn[2], pn[3]);
    *(float4*)(qout + q0o)         = make_float4(q0n[0], q0n[1], q0n[2], q0n[3]);
    *(float4*)(qout + q0o + VOL)   = make_float4(q1n[0], q1n[1], q1n[2], q1n[3]);
    *(float4*)(qout + q0o + 2*VOL) = make_float4(q2n[0], q2n[1], q2n[2], q2n[3]);
    *(float4*)(x1out + off)        = make_float4(x1v[0], x1v[1], x1v[2], x1v[3]);
    *(float4*)(xbout + off)        = make_float4(xbn[0], xbn[1], xbn[2], xbn[3]);
}

extern "C" void kernel_launch(void* const* d_in, const int* in_sizes, int n_in,
                              void* d_out, int out_size, void* d_ws, size_t ws_size,
                              hipStream_t stream) {
    const float* x   = (const float*)d_in[0];
    const float* lam = (const float*)d_in[1];
    float* out = (float*)d_out;
    float* ws  = (float*)d_ws;

    const double s10 = 1.0 / (1.0 + exp(-10.0));
    const double L   = sqrt(13.0);
    float sigma  = (float)(s10 / L);
    float tau    = sigma;
    float theta  = (float)s10;
    float inv1ps = (float)(1.0 / (1.0 + s10 / L));

    // ---- try cooperative persistent kernel ----
    // ws layout (coop): xbA | xbB | q0A | q0B | q1A | q1B = 6*NX floats
    float* xbA = ws;
    float* xbB = ws + (size_t)NX;
    float* q0A = ws + (size_t)2 * NX;
    float* q0B = ws + (size_t)3 * NX;
    float* q1A = ws + (size_t)4 * NX;
    float* q1B = ws + (size_t)5 * NX;

    void* args[] = {
        (void*)&x, (void*)&lam, (void*)&out,
        (void*)&xbA, (void*)&xbB, (void*)&q0A, (void*)&q0B,
        (void*)&q1A, (void*)&q1B,
        (void*)&sigma, (void*)&inv1ps, (void*)&tau, (void*)&theta
    };
    hipError_t err = hipLaunchCooperativeKernel((const void*)pd_persistent,
                                                dim3(NBLOCKS), dim3(256), args,
                                                0, stream);
    if (err == hipSuccess) return;

    // ---- fallback: proven 48-launch path ----
    // ws layout (fallback): xbuf | p | xbarA | xbarB | qA | qB = 10*NX floats
    float* xbuf  = ws;
    float* p     = ws + (size_t)NX;
    float* xbarA = ws + (size_t)2 * NX;
    float* xbarB = ws + (size_t)3 * NX;
    float* qA    = ws + (size_t)4 * NX;
    float* qB    = ws + (size_t)4 * NX + NQ;

    init_kernel<<<(NQ + 255) / 256, 256, 0, stream>>>(x, xbuf, p, xbarA, qA);

    const int nthreads = NX / 4;
    dim3 grid((nthreads + 255) / 256), block(256);

    for (int it = 0; it < T_ITERS; ++it) {
        const float* qin  = (it & 1) ? qB : qA;
        float*       qout = (it & 1) ? qA : qB;
        const float* xbin = (it & 1) ? xbarB : xbarA;
        float*       xbout= (it & 1) ? xbarA : xbarB;
        float*       x1o  = (it == T_ITERS - 1) ? out : xbuf;
        step_kernel<<<grid, block, 0, stream>>>(x, p, qin, qout, xbuf, x1o,
                                                xbin, xbout, lam,
                                                sigma, inv1ps, tau, theta);
    }
}

// Round 4
// 413.705 us; speedup vs baseline: 20.3833x; 20.3833x over previous
//
#include <hip/hip_runtime.h>
#include <math.h>

// Problem dims: x (2,1,160,160,16) f32, lambda (2,3,160,160,16) f32, 48 iters.
// K=2 temporal fusion: each launch advances state by 2 PD iterations using
// LDS-staged xbar halos + bit-identical neighbor-q recompute.
#define XDIM 160
#define YDIM 160
#define TDIM 16
#define NB 2
#define T_ITERS 48
#define TILE 8
#define H1S (TILE + 2)   // 10: iter1 output region (dilate 1)
#define H2S (TILE + 4)   // 12: xbar_0 staging region (dilate 2)
#define TPT (XDIM / TILE) // 20 tiles per side

constexpr int VOL = XDIM * YDIM * TDIM;   // 409600
constexpr int NX  = NB * VOL;             // 819200
constexpr int NBLK = NB * TPT * TPT;      // 800 blocks

__device__ __forceinline__ float clampl(float v, float l) {
    return fminf(fmaxf(v, -l), l);
}
__device__ __forceinline__ int wrap(int v) {  // v in [-2, XDIM+1]
    return v < 0 ? v + XDIM : (v >= XDIM ? v - XDIM : v);
}

__global__ __launch_bounds__(256) void init_kernel(
    const float* __restrict__ x, float* __restrict__ pA, float* __restrict__ xA,
    float* __restrict__ xbA, float* __restrict__ qA)
{
    int i = blockIdx.x * blockDim.x + threadIdx.x;
    if (i < NX) {
        float v = x[i];
        pA[i] = v; xA[i] = v; xbA[i] = v;
    }
    if (i < 3 * NX) qA[i] = 0.0f;
}

// One PD iteration at line (gx,gy), t-quad t0, using xbar_0 from LDS (H2 coords
// hx1+1,hy1+1). Writes xbar_1 to LDS (H1 coords hx1,hy1). Returns register state
// needed by iter2 (dead-code-eliminated at halo call sites).
__device__ __forceinline__ void iter1_compute(
    const float* __restrict__ xn, const float* __restrict__ lam,
    const float* __restrict__ pIn, const float* __restrict__ xIn,
    const float* __restrict__ qIn,
    const float* __restrict__ xb0, float* __restrict__ xb1,
    int b, int gx, int gy, int t0, int hx1, int hy1,
    float sigma, float inv1ps, float tau, float theta,
    float* pn, float* x1v, float* q0n, float* q1n, float* q2n,
    float* q0xm, float* q1ym,
    float* l0c, float* l1c, float* l2c, float* l0m, float* l1m, float* xnc)
{
    const int gxm = wrap(gx - 1), gym = wrap(gy - 1);
    const int xbase = b * VOL, qbase = b * 3 * VOL;
    const int lineC  = (gx * YDIM + gy) * TDIM;
    const int lineXM = (gxm * YDIM + gy) * TDIM;
    const int lineYM = (gx * YDIM + gym) * TDIM;
    const int off = xbase + lineC + t0;

    const float4 P0   = *(const float4*)(pIn + off);
    const float4 X0   = *(const float4*)(xIn + off);
    const float4 XN   = *(const float4*)(xn + off);
    const float4 Q0C  = *(const float4*)(qIn + qbase + lineC + t0);
    const float4 Q0XM = *(const float4*)(qIn + qbase + lineXM + t0);
    const float4 Q1C  = *(const float4*)(qIn + qbase + VOL + lineC + t0);
    const float4 Q1YM = *(const float4*)(qIn + qbase + VOL + lineYM + t0);
    const float4 Q2C  = *(const float4*)(qIn + qbase + 2 * VOL + lineC + t0);
    const float  Q2TM = qIn[qbase + 2 * VOL + lineC + ((t0 + TDIM - 1) & (TDIM - 1))];
    const float4 L0C  = *(const float4*)(lam + qbase + lineC + t0);
    const float4 L0M  = *(const float4*)(lam + qbase + lineXM + t0);
    const float4 L1C  = *(const float4*)(lam + qbase + VOL + lineC + t0);
    const float4 L1M  = *(const float4*)(lam + qbase + VOL + lineYM + t0);
    const float4 L2C  = *(const float4*)(lam + qbase + 2 * VOL + lineC + t0);
    const float  L2TM = lam[qbase + 2 * VOL + lineC + ((t0 + TDIM - 1) & (TDIM - 1))];

    // xbar_0 from LDS (H2 coords: H1 + 1)
    const int h2c  = ((hx1 + 1) * H2S + (hy1 + 1)) * TDIM;
    const int h2xp = ((hx1 + 2) * H2S + (hy1 + 1)) * TDIM;
    const int h2xm = ((hx1    ) * H2S + (hy1 + 1)) * TDIM;
    const int h2yp = ((hx1 + 1) * H2S + (hy1 + 2)) * TDIM;
    const int h2ym = ((hx1 + 1) * H2S + (hy1    )) * TDIM;

    const float4 XBC  = *(const float4*)(xb0 + h2c + t0);
    const float4 XBXP = *(const float4*)(xb0 + h2xp + t0);
    const float4 XBXM = *(const float4*)(xb0 + h2xm + t0);
    const float4 XBYP = *(const float4*)(xb0 + h2yp + t0);
    const float4 XBYM = *(const float4*)(xb0 + h2ym + t0);
    const float xb_tm = xb0[h2c + ((t0 + TDIM - 1) & (TDIM - 1))];
    const float xb_tp = xb0[h2c + ((t0 + 4) & (TDIM - 1))];

    float xbc[4]  = {XBC.x, XBC.y, XBC.z, XBC.w};
    float xbxp[4] = {XBXP.x, XBXP.y, XBXP.z, XBXP.w};
    float xbxm[4] = {XBXM.x, XBXM.y, XBXM.z, XBXM.w};
    float xbyp[4] = {XBYP.x, XBYP.y, XBYP.z, XBYP.w};
    float xbym[4] = {XBYM.x, XBYM.y, XBYM.z, XBYM.w};
    float pc[4]   = {P0.x, P0.y, P0.z, P0.w};
    float x0c[4]  = {X0.x, X0.y, X0.z, X0.w};
    float q0c[4]  = {Q0C.x, Q0C.y, Q0C.z, Q0C.w};
    float q1c[4]  = {Q1C.x, Q1C.y, Q1C.z, Q1C.w};
    float q2c[4]  = {Q2C.x, Q2C.y, Q2C.z, Q2C.w};

    xnc[0]=XN.x; xnc[1]=XN.y; xnc[2]=XN.z; xnc[3]=XN.w;
    q0xm[0]=Q0XM.x; q0xm[1]=Q0XM.y; q0xm[2]=Q0XM.z; q0xm[3]=Q0XM.w;
    q1ym[0]=Q1YM.x; q1ym[1]=Q1YM.y; q1ym[2]=Q1YM.z; q1ym[3]=Q1YM.w;
    l0c[0]=L0C.x; l0c[1]=L0C.y; l0c[2]=L0C.z; l0c[3]=L0C.w;
    l1c[0]=L1C.x; l1c[1]=L1C.y; l1c[2]=L1C.z; l1c[3]=L1C.w;
    l2c[0]=L2C.x; l2c[1]=L2C.y; l2c[2]=L2C.z; l2c[3]=L2C.w;
    l0m[0]=L0M.x; l0m[1]=L0M.y; l0m[2]=L0M.z; l0m[3]=L0M.w;
    l1m[0]=L1M.x; l1m[1]=L1M.y; l1m[2]=L1M.z; l1m[3]=L1M.w;

    float xbn[4];
    #pragma unroll
    for (int j = 0; j < 4; ++j) {
        pn[j] = (pc[j] + sigma * (xbc[j] - xnc[j])) * inv1ps;

        float gx1 = xbxp[j] - xbc[j];
        float gy1 = xbyp[j] - xbc[j];
        float gt1 = ((j < 3) ? xbc[j + 1] : xb_tp) - xbc[j];

        q0n[j] = clampl(q0c[j] + sigma * gx1, l0c[j]);
        q1n[j] = clampl(q1c[j] + sigma * gy1, l1c[j]);
        q2n[j] = clampl(q2c[j] + sigma * gt1, l2c[j]);

        float q0m = clampl(q0xm[j] + sigma * (xbc[j] - xbxm[j]), l0m[j]);
        float q1m = clampl(q1ym[j] + sigma * (xbc[j] - xbym[j]), l1m[j]);
        float gtm    = xbc[j] - ((j == 0) ? xb_tm : xbc[j - 1]);
        float q2prev = (j == 0) ? Q2TM : q2c[j - 1];
        float l2prev = (j == 0) ? L2TM : l2c[j - 1];
        float q2m = clampl(q2prev + sigma * gtm, l2prev);

        float div = (q0m - q0n[j]) + (q1m - q1n[j]) + (q2m - q2n[j]);

        x1v[j] = x0c[j] - tau * (pn[j] + div);
        xbn[j] = x1v[j] + theta * (x1v[j] - x0c[j]);
    }

    const int h1c = (hx1 * H1S + hy1) * TDIM;
    *(float4*)(xb1 + h1c + t0) = make_float4(xbn[0], xbn[1], xbn[2], xbn[3]);
}

// Two fused PD iterations per launch.
__global__ __launch_bounds__(256, 3) void pd_step2(
    const float* __restrict__ xn, const float* __restrict__ lam,
    const float* __restrict__ pIn, float* __restrict__ pOut,
    const float* __restrict__ xIn, float* __restrict__ xOut,
    const float* __restrict__ xbIn, float* __restrict__ xbOut,
    const float* __restrict__ qIn, float* __restrict__ qOut,
    float sigma, float inv1ps, float tau, float theta)
{
    __shared__ float xb0[H2S * H2S * TDIM];  // 9.2 KB
    __shared__ float xb1[H1S * H1S * TDIM];  // 6.4 KB

    const int tid = threadIdx.x;
    const int b    = blockIdx.x / (TPT * TPT);
    const int rem  = blockIdx.x % (TPT * TPT);
    const int x0g  = (rem / TPT) * TILE;
    const int y0g  = (rem % TPT) * TILE;
    const int xbase = b * VOL, qbase = b * 3 * VOL;

    // ---- stage xbar_0 over 12x12 halo tile into LDS ----
    for (int s = tid; s < H2S * H2S * 4; s += 256) {
        int quad = s & 3, hl = s >> 2;
        int gx = wrap(x0g + hl / H2S - 2);
        int gy = wrap(y0g + hl % H2S - 2);
        *(float4*)(xb0 + hl * TDIM + quad * 4) =
            *(const float4*)(xbIn + xbase + (gx * YDIM + gy) * TDIM + quad * 4);
    }
    __syncthreads();

    // ---- iter1 on halo ring first (short register lifetimes) ----
    if (tid < 144) {   // 36 halo lines x 4 quads
        int quad = tid & 3, hl = tid >> 2;   // hl in [0,36)
        int hhx, hhy;
        if (hl < 10)      { hhx = 0; hhy = hl; }
        else if (hl < 20) { hhx = 9; hhy = hl - 10; }
        else              { int r = hl - 20; hhx = 1 + (r >> 1); hhy = (r & 1) * 9; }
        int ggx = wrap(x0g + hhx - 1), ggy = wrap(y0g + hhy - 1);
        float d0[4],d1[4],d2[4],d3[4],d4[4],d5[4],d6[4],
              d7[4],d8[4],d9[4],d10[4],d11[4],d12[4];
        iter1_compute(xn, lam, pIn, xIn, qIn, xb0, xb1,
                      b, ggx, ggy, quad * 4, hhx, hhy,
                      sigma, inv1ps, tau, theta,
                      d0,d1,d2,d3,d4,d5,d6,d7,d8,d9,d10,d11,d12);
    }

    // ---- iter1 on own center quad (keep state in registers) ----
    const int t0 = (tid & 3) * 4;
    const int cline = tid >> 2;                 // 0..63
    const int cx = cline >> 3, cy = cline & 7;  // 8x8
    const int hx1 = cx + 1, hy1 = cy + 1;
    const int gx = x0g + cx, gy = y0g + cy;
    float pn[4], x1v[4], q0n[4], q1n[4], q2n[4], q0xm[4], q1ym[4];
    float l0c[4], l1c[4], l2c[4], l0m[4], l1m[4], xnc[4];
    iter1_compute(xn, lam, pIn, xIn, qIn, xb0, xb1,
                  b, gx, gy, t0, hx1, hy1,
                  sigma, inv1ps, tau, theta,
                  pn, x1v, q0n, q1n, q2n, q0xm, q1ym,
                  l0c, l1c, l2c, l0m, l1m, xnc);
    __syncthreads();

    // ---- iter2 on center using LDS xbar_1 + register state ----
    const int h1c  = (hx1 * H1S + hy1) * TDIM;
    const int h1xp = ((hx1 + 1) * H1S + hy1) * TDIM;
    const int h1xm = ((hx1 - 1) * H1S + hy1) * TDIM;
    const int h1yp = (hx1 * H1S + (hy1 + 1)) * TDIM;
    const int h1ym = (hx1 * H1S + (hy1 - 1)) * TDIM;
    const float4 B1C  = *(const float4*)(xb1 + h1c + t0);
    const float4 B1XP = *(const float4*)(xb1 + h1xp + t0);
    const float4 B1XM = *(const float4*)(xb1 + h1xm + t0);
    const float4 B1YP = *(const float4*)(xb1 + h1yp + t0);
    const float4 B1YM = *(const float4*)(xb1 + h1ym + t0);
    const float xb1_tm = xb1[h1c + ((t0 + TDIM - 1) & (TDIM - 1))];
    const float xb1_tp = xb1[h1c + ((t0 + 4) & (TDIM - 1))];

    const int h2c  = ((hx1 + 1) * H2S + (hy1 + 1)) * TDIM;
    const int h2xm = ((hx1    ) * H2S + (hy1 + 1)) * TDIM;
    const int h2ym = ((hx1 + 1) * H2S + (hy1    )) * TDIM;
    const float4 B0C  = *(const float4*)(xb0 + h2c + t0);
    const float4 B0XM = *(const float4*)(xb0 + h2xm + t0);
    const float4 B0YM = *(const float4*)(xb0 + h2ym + t0);

    float xb1c[4]  = {B1C.x, B1C.y, B1C.z, B1C.w};
    float xb1xp[4] = {B1XP.x, B1XP.y, B1XP.z, B1XP.w};
    float xb1xm[4] = {B1XM.x, B1XM.y, B1XM.z, B1XM.w};
    float xb1yp[4] = {B1YP.x, B1YP.y, B1YP.z, B1YP.w};
    float xb1ym[4] = {B1YM.x, B1YM.y, B1YM.z, B1YM.w};
    float xb0c[4]  = {B0C.x, B0C.y, B0C.z, B0C.w};
    float xb0xm[4] = {B0XM.x, B0XM.y, B0XM.z, B0XM.w};
    float xb0ym[4] = {B0YM.x, B0YM.y, B0YM.z, B0YM.w};

    const int lane  = tid & 63;
    const int dnSrc = (lane & 60) | ((lane + 3) & 3);
    const float q2_1_tm = __shfl(q2n[3], dnSrc, 64);  // q2_1 at t0-1 (prev quad)
    const float l2p     = __shfl(l2c[3], dnSrc, 64);  // lam2 at t0-1

    float p2[4], q02[4], q12[4], q22[4], x2[4], xb2[4];
    #pragma unroll
    for (int j = 0; j < 4; ++j) {
        p2[j] = (pn[j] + sigma * (xb1c[j] - xnc[j])) * inv1ps;

        float gx1 = xb1xp[j] - xb1c[j];
        float gy1 = xb1yp[j] - xb1c[j];
        float gt1 = ((j < 3) ? xb1c[j + 1] : xb1_tp) - xb1c[j];
        q02[j] = clampl(q0n[j] + sigma * gx1, l0c[j]);
        q12[j] = clampl(q1n[j] + sigma * gy1, l1c[j]);
        q22[j] = clampl(q2n[j] + sigma * gt1, l2c[j]);

        // iter2 q at backward neighbors: recompute iter1 neighbor q, then advance
        float q0_1m = clampl(q0xm[j] + sigma * (xb0c[j] - xb0xm[j]), l0m[j]);
        float q0_2m = clampl(q0_1m + sigma * (xb1c[j] - xb1xm[j]), l0m[j]);
        float q1_1m = clampl(q1ym[j] + sigma * (xb0c[j] - xb0ym[j]), l1m[j]);
        float q1_2m = clampl(q1_1m + sigma * (xb1c[j] - xb1ym[j]), l1m[j]);
        float q2_1m  = (j == 0) ? q2_1_tm : q2n[j - 1];
        float l2m    = (j == 0) ? l2p     : l2c[j - 1];
        float xb1tm  = (j == 0) ? xb1_tm  : xb1c[j - 1];
        float q2_2m = clampl(q2_1m + sigma * (xb1c[j] - xb1tm), l2m);

        float div = (q0_2m - q02[j]) + (q1_2m - q12[j]) + (q2_2m - q22[j]);

        x2[j]  = x1v[j] - tau * (p2[j] + div);
        xb2[j] = x2[j] + theta * (x2[j] - x1v[j]);
    }

    const int off  = xbase + (gx * YDIM + gy) * TDIM + t0;
    const int qoff = qbase + (gx * YDIM + gy) * TDIM + t0;
    *(float4*)(pOut + off)          = make_float4(p2[0], p2[1], p2[2], p2[3]);
    *(float4*)(qOut + qoff)         = make_float4(q02[0], q02[1], q02[2], q02[3]);
    *(float4*)(qOut + qoff + VOL)   = make_float4(q12[0], q12[1], q12[2], q12[3]);
    *(float4*)(qOut + qoff + 2*VOL) = make_float4(q22[0], q22[1], q22[2], q22[3]);
    *(float4*)(xOut + off)          = make_float4(x2[0], x2[1], x2[2], x2[3]);
    *(float4*)(xbOut + off)         = make_float4(xb2[0], xb2[1], xb2[2], xb2[3]);
}

extern "C" void kernel_launch(void* const* d_in, const int* in_sizes, int n_in,
                              void* d_out, int out_size, void* d_ws, size_t ws_size,
                              hipStream_t stream) {
    const float* x   = (const float*)d_in[0];
    const float* lam = (const float*)d_in[1];
    float* out = (float*)d_out;
    float* ws  = (float*)d_ws;

    // ws (11*NX floats = 36.0 MB): pA pB xbA xbB qA(3) qB(3) xB ; xA aliases d_out
    float* pA  = ws;
    float* pB  = ws + (size_t)NX;
    float* xbA = ws + (size_t)2 * NX;
    float* xbB = ws + (size_t)3 * NX;
    float* qA  = ws + (size_t)4 * NX;
    float* qB  = ws + (size_t)7 * NX;
    float* xBb = ws + (size_t)10 * NX;
    float* xAb = out;   // launch 23 (odd) writes the A family -> x_48 lands in d_out

    const double s10 = 1.0 / (1.0 + exp(-10.0));
    const double L   = sqrt(13.0);
    float sigma  = (float)(s10 / L);
    float tau    = sigma;
    float theta  = (float)s10;
    float inv1ps = (float)(1.0 / (1.0 + s10 / L));

    init_kernel<<<(3 * NX + 255) / 256, 256, 0, stream>>>(x, pA, xAb, xbA, qA);

    for (int j = 0; j < T_ITERS / 2; ++j) {
        const bool e = (j & 1) == 0;
        pd_step2<<<NBLK, 256, 0, stream>>>(
            x, lam,
            e ? pA : pB,  e ? pB : pA,
            e ? xAb : xBb, e ? xBb : xAb,
            e ? xbA : xbB, e ? xbB : xbA,
            e ? qA : qB,  e ? qB : qA,
            sigma, inv1ps, tau, theta);
    }
}

// Round 5
// 355.432 us; speedup vs baseline: 23.7252x; 1.1640x over previous
//
#include <hip/hip_runtime.h>
#include <math.h>

// K=2 temporal fusion (R3 structure) + fp16 storage for q/xbar/lambda/xn.
// p, x remain fp32 (they integrate). Intra-launch math is all fp32; fp16
// rounding happens only at launch boundaries (once per 2 PD iterations).
#define XDIM 160
#define YDIM 160
#define TDIM 16
#define NB 2
#define T_ITERS 48
#define TILE 8
#define H1S (TILE + 2)    // 10: iter1 output region (dilate 1)
#define H2S (TILE + 4)    // 12: xbar_0 staging region (dilate 2)
#define TPT (XDIM / TILE) // 20 tiles per side

constexpr int VOL  = XDIM * YDIM * TDIM;  // 409600
constexpr int NX   = NB * VOL;            // 819200
constexpr int NBLK = NB * TPT * TPT;      // 800 blocks

typedef _Float16 hreal;
typedef _Float16 half4 __attribute__((ext_vector_type(4)));

__device__ __forceinline__ float clampl(float v, float l) {
    return fminf(fmaxf(v, -l), l);
}
__device__ __forceinline__ int wrap(int v) {
    return v < 0 ? v + XDIM : (v >= XDIM ? v - XDIM : v);
}

__global__ __launch_bounds__(256) void init_kernel(
    const float* __restrict__ x, const float* __restrict__ lam,
    float* __restrict__ pA, float* __restrict__ xA,
    hreal* __restrict__ xbAh, hreal* __restrict__ qAh,
    hreal* __restrict__ lamh, hreal* __restrict__ xnh)
{
    int i = blockIdx.x * blockDim.x + threadIdx.x;
    if (i < NX) {
        float v = x[i];
        pA[i] = v; xA[i] = v;
        xbAh[i] = (hreal)v;
        xnh[i]  = (hreal)v;
    }
    if (i < 3 * NX) {
        qAh[i]  = (hreal)0.f;
        lamh[i] = (hreal)lam[i];
    }
}

// One PD iteration at line (gx,gy), t-quad t0, xbar_0 from LDS (fp32),
// writes xbar_1 (fp32) to LDS. Returns register state for iter2.
__device__ __forceinline__ void iter1_compute(
    const hreal* __restrict__ xnh, const hreal* __restrict__ lamh,
    const float* __restrict__ pIn, const float* __restrict__ xIn,
    const hreal* __restrict__ qIn,
    const float* __restrict__ xb0, float* __restrict__ xb1,
    int b, int gx, int gy, int t0, int hx1, int hy1,
    float sigma, float inv1ps, float tau, float theta,
    float* pn, float* x1v, float* q0n, float* q1n, float* q2n,
    float* q0xm, float* q1ym,
    float* l0c, float* l1c, float* l2c, float* l0m, float* l1m, float* xnc)
{
    const int gxm = wrap(gx - 1), gym = wrap(gy - 1);
    const int xbase = b * VOL, qbase = b * 3 * VOL;
    const int lineC  = (gx * YDIM + gy) * TDIM;
    const int lineXM = (gxm * YDIM + gy) * TDIM;
    const int lineYM = (gx * YDIM + gym) * TDIM;
    const int off = xbase + lineC + t0;

    const float4 P0   = *(const float4*)(pIn + off);
    const float4 X0   = *(const float4*)(xIn + off);
    const half4  XN   = *(const half4*)(xnh + off);
    const half4  Q0C  = *(const half4*)(qIn + qbase + lineC + t0);
    const half4  Q0XM = *(const half4*)(qIn + qbase + lineXM + t0);
    const half4  Q1C  = *(const half4*)(qIn + qbase + VOL + lineC + t0);
    const half4  Q1YM = *(const half4*)(qIn + qbase + VOL + lineYM + t0);
    const half4  Q2C  = *(const half4*)(qIn + qbase + 2 * VOL + lineC + t0);
    const float  Q2TM = (float)qIn[qbase + 2 * VOL + lineC + ((t0 + TDIM - 1) & (TDIM - 1))];
    const half4  L0C  = *(const half4*)(lamh + qbase + lineC + t0);
    const half4  L0M  = *(const half4*)(lamh + qbase + lineXM + t0);
    const half4  L1C  = *(const half4*)(lamh + qbase + VOL + lineC + t0);
    const half4  L1M  = *(const half4*)(lamh + qbase + VOL + lineYM + t0);
    const half4  L2C  = *(const half4*)(lamh + qbase + 2 * VOL + lineC + t0);
    const float  L2TM = (float)lamh[qbase + 2 * VOL + lineC + ((t0 + TDIM - 1) & (TDIM - 1))];

    const int h2c  = ((hx1 + 1) * H2S + (hy1 + 1)) * TDIM;
    const int h2xp = ((hx1 + 2) * H2S + (hy1 + 1)) * TDIM;
    const int h2xm = ((hx1    ) * H2S + (hy1 + 1)) * TDIM;
    const int h2yp = ((hx1 + 1) * H2S + (hy1 + 2)) * TDIM;
    const int h2ym = ((hx1 + 1) * H2S + (hy1    )) * TDIM;

    const float4 XBC  = *(const float4*)(xb0 + h2c + t0);
    const float4 XBXP = *(const float4*)(xb0 + h2xp + t0);
    const float4 XBXM = *(const float4*)(xb0 + h2xm + t0);
    const float4 XBYP = *(const float4*)(xb0 + h2yp + t0);
    const float4 XBYM = *(const float4*)(xb0 + h2ym + t0);
    const float xb_tm = xb0[h2c + ((t0 + TDIM - 1) & (TDIM - 1))];
    const float xb_tp = xb0[h2c + ((t0 + 4) & (TDIM - 1))];

    float xbc[4]  = {XBC.x, XBC.y, XBC.z, XBC.w};
    float xbxp[4] = {XBXP.x, XBXP.y, XBXP.z, XBXP.w};
    float xbxm[4] = {XBXM.x, XBXM.y, XBXM.z, XBXM.w};
    float xbyp[4] = {XBYP.x, XBYP.y, XBYP.z, XBYP.w};
    float xbym[4] = {XBYM.x, XBYM.y, XBYM.z, XBYM.w};
    float pc[4]   = {P0.x, P0.y, P0.z, P0.w};
    float x0c[4]  = {X0.x, X0.y, X0.z, X0.w};
    float q0c[4]  = {(float)Q0C.x, (float)Q0C.y, (float)Q0C.z, (float)Q0C.w};
    float q1c[4]  = {(float)Q1C.x, (float)Q1C.y, (float)Q1C.z, (float)Q1C.w};
    float q2c[4]  = {(float)Q2C.x, (float)Q2C.y, (float)Q2C.z, (float)Q2C.w};

    xnc[0]=(float)XN.x; xnc[1]=(float)XN.y; xnc[2]=(float)XN.z; xnc[3]=(float)XN.w;
    q0xm[0]=(float)Q0XM.x; q0xm[1]=(float)Q0XM.y; q0xm[2]=(float)Q0XM.z; q0xm[3]=(float)Q0XM.w;
    q1ym[0]=(float)Q1YM.x; q1ym[1]=(float)Q1YM.y; q1ym[2]=(float)Q1YM.z; q1ym[3]=(float)Q1YM.w;
    l0c[0]=(float)L0C.x; l0c[1]=(float)L0C.y; l0c[2]=(float)L0C.z; l0c[3]=(float)L0C.w;
    l1c[0]=(float)L1C.x; l1c[1]=(float)L1C.y; l1c[2]=(float)L1C.z; l1c[3]=(float)L1C.w;
    l2c[0]=(float)L2C.x; l2c[1]=(float)L2C.y; l2c[2]=(float)L2C.z; l2c[3]=(float)L2C.w;
    l0m[0]=(float)L0M.x; l0m[1]=(float)L0M.y; l0m[2]=(float)L0M.z; l0m[3]=(float)L0M.w;
    l1m[0]=(float)L1M.x; l1m[1]=(float)L1M.y; l1m[2]=(float)L1M.z; l1m[3]=(float)L1M.w;

    float xbn[4];
    #pragma unroll
    for (int j = 0; j < 4; ++j) {
        pn[j] = (pc[j] + sigma * (xbc[j] - xnc[j])) * inv1ps;

        float gx1 = xbxp[j] - xbc[j];
        float gy1 = xbyp[j] - xbc[j];
        float gt1 = ((j < 3) ? xbc[j + 1] : xb_tp) - xbc[j];

        q0n[j] = clampl(q0c[j] + sigma * gx1, l0c[j]);
        q1n[j] = clampl(q1c[j] + sigma * gy1, l1c[j]);
        q2n[j] = clampl(q2c[j] + sigma * gt1, l2c[j]);

        float q0m = clampl(q0xm[j] + sigma * (xbc[j] - xbxm[j]), l0m[j]);
        float q1m = clampl(q1ym[j] + sigma * (xbc[j] - xbym[j]), l1m[j]);
        float gtm    = xbc[j] - ((j == 0) ? xb_tm : xbc[j - 1]);
        float q2prev = (j == 0) ? Q2TM : q2c[j - 1];
        float l2prev = (j == 0) ? L2TM : l2c[j - 1];
        float q2m = clampl(q2prev + sigma * gtm, l2prev);

        float div = (q0m - q0n[j]) + (q1m - q1n[j]) + (q2m - q2n[j]);

        x1v[j] = x0c[j] - tau * (pn[j] + div);
        xbn[j] = x1v[j] + theta * (x1v[j] - x0c[j]);
    }

    const int h1c = (hx1 * H1S + hy1) * TDIM;
    *(float4*)(xb1 + h1c + t0) = make_float4(xbn[0], xbn[1], xbn[2], xbn[3]);
}

// Two fused PD iterations per launch.
__global__ __launch_bounds__(256, 3) void pd_step2(
    const hreal* __restrict__ xnh, const hreal* __restrict__ lamh,
    const float* __restrict__ pIn, float* __restrict__ pOut,
    const float* __restrict__ xIn, float* __restrict__ xOut,
    const hreal* __restrict__ xbIn, hreal* __restrict__ xbOut,
    const hreal* __restrict__ qIn, hreal* __restrict__ qOut,
    float sigma, float inv1ps, float tau, float theta)
{
    __shared__ float xb0[H2S * H2S * TDIM];  // 9.2 KB (fp32 working copy)
    __shared__ float xb1[H1S * H1S * TDIM];  // 6.4 KB

    const int tid = threadIdx.x;
    const int b    = blockIdx.x / (TPT * TPT);
    const int rem  = blockIdx.x % (TPT * TPT);
    const int x0g  = (rem / TPT) * TILE;
    const int y0g  = (rem % TPT) * TILE;
    const int xbase = b * VOL, qbase = b * 3 * VOL;

    // ---- stage xbar_0 (fp16 -> fp32) over 12x12 halo tile into LDS ----
    for (int s = tid; s < H2S * H2S * 4; s += 256) {
        int quad = s & 3, hl = s >> 2;
        int gx = wrap(x0g + hl / H2S - 2);
        int gy = wrap(y0g + hl % H2S - 2);
        const half4 H = *(const half4*)(xbIn + xbase + (gx * YDIM + gy) * TDIM + quad * 4);
        *(float4*)(xb0 + hl * TDIM + quad * 4) =
            make_float4((float)H.x, (float)H.y, (float)H.z, (float)H.w);
    }
    __syncthreads();

    // ---- iter1 on halo ring first ----
    if (tid < 144) {   // 36 halo lines x 4 quads
        int quad = tid & 3, hl = tid >> 2;
        int hhx, hhy;
        if (hl < 10)      { hhx = 0; hhy = hl; }
        else if (hl < 20) { hhx = 9; hhy = hl - 10; }
        else              { int r = hl - 20; hhx = 1 + (r >> 1); hhy = (r & 1) * 9; }
        int ggx = wrap(x0g + hhx - 1), ggy = wrap(y0g + hhy - 1);
        float d0[4],d1[4],d2[4],d3[4],d4[4],d5[4],d6[4],
              d7[4],d8[4],d9[4],d10[4],d11[4],d12[4];
        iter1_compute(xnh, lamh, pIn, xIn, qIn, xb0, xb1,
                      b, ggx, ggy, quad * 4, hhx, hhy,
                      sigma, inv1ps, tau, theta,
                      d0,d1,d2,d3,d4,d5,d6,d7,d8,d9,d10,d11,d12);
    }

    // ---- iter1 on own center quad (state stays in registers) ----
    const int t0 = (tid & 3) * 4;
    const int cline = tid >> 2;
    const int cx = cline >> 3, cy = cline & 7;
    const int hx1 = cx + 1, hy1 = cy + 1;
    const int gx = x0g + cx, gy = y0g + cy;
    float pn[4], x1v[4], q0n[4], q1n[4], q2n[4], q0xm[4], q1ym[4];
    float l0c[4], l1c[4], l2c[4], l0m[4], l1m[4], xnc[4];
    iter1_compute(xnh, lamh, pIn, xIn, qIn, xb0, xb1,
                  b, gx, gy, t0, hx1, hy1,
                  sigma, inv1ps, tau, theta,
                  pn, x1v, q0n, q1n, q2n, q0xm, q1ym,
                  l0c, l1c, l2c, l0m, l1m, xnc);
    __syncthreads();

    // ---- iter2 on center using LDS xbar_1 + register state ----
    const int h1c  = (hx1 * H1S + hy1) * TDIM;
    const int h1xp = ((hx1 + 1) * H1S + hy1) * TDIM;
    const int h1xm = ((hx1 - 1) * H1S + hy1) * TDIM;
    const int h1yp = (hx1 * H1S + (hy1 + 1)) * TDIM;
    const int h1ym = (hx1 * H1S + (hy1 - 1)) * TDIM;
    const float4 B1C  = *(const float4*)(xb1 + h1c + t0);
    const float4 B1XP = *(const float4*)(xb1 + h1xp + t0);
    const float4 B1XM = *(const float4*)(xb1 + h1xm + t0);
    const float4 B1YP = *(const float4*)(xb1 + h1yp + t0);
    const float4 B1YM = *(const float4*)(xb1 + h1ym + t0);
    const float xb1_tm = xb1[h1c + ((t0 + TDIM - 1) & (TDIM - 1))];
    const float xb1_tp = xb1[h1c + ((t0 + 4) & (TDIM - 1))];

    const int h2c  = ((hx1 + 1) * H2S + (hy1 + 1)) * TDIM;
    const int h2xm = ((hx1    ) * H2S + (hy1 + 1)) * TDIM;
    const int h2ym = ((hx1 + 1) * H2S + (hy1    )) * TDIM;
    const float4 B0C  = *(const float4*)(xb0 + h2c + t0);
    const float4 B0XM = *(const float4*)(xb0 + h2xm + t0);
    const float4 B0YM = *(const float4*)(xb0 + h2ym + t0);

    float xb1c[4]  = {B1C.x, B1C.y, B1C.z, B1C.w};
    float xb1xp[4] = {B1XP.x, B1XP.y, B1XP.z, B1XP.w};
    float xb1xm[4] = {B1XM.x, B1XM.y, B1XM.z, B1XM.w};
    float xb1yp[4] = {B1YP.x, B1YP.y, B1YP.z, B1YP.w};
    float xb1ym[4] = {B1YM.x, B1YM.y, B1YM.z, B1YM.w};
    float xb0c[4]  = {B0C.x, B0C.y, B0C.z, B0C.w};
    float xb0xm[4] = {B0XM.x, B0XM.y, B0XM.z, B0XM.w};
    float xb0ym[4] = {B0YM.x, B0YM.y, B0YM.z, B0YM.w};

    const int lane  = tid & 63;
    const int dnSrc = (lane & 60) | ((lane + 3) & 3);
    const float q2_1_tm = __shfl(q2n[3], dnSrc, 64);
    const float l2p     = __shfl(l2c[3], dnSrc, 64);

    float p2[4], q02[4], q12[4], q22[4], x2[4], xb2[4];
    #pragma unroll
    for (int j = 0; j < 4; ++j) {
        p2[j] = (pn[j] + sigma * (xb1c[j] - xnc[j])) * inv1ps;

        float gx1 = xb1xp[j] - xb1c[j];
        float gy1 = xb1yp[j] - xb1c[j];
        float gt1 = ((j < 3) ? xb1c[j + 1] : xb1_tp) - xb1c[j];
        q02[j] = clampl(q0n[j] + sigma * gx1, l0c[j]);
        q12[j] = clampl(q1n[j] + sigma * gy1, l1c[j]);
        q22[j] = clampl(q2n[j] + sigma * gt1, l2c[j]);

        float q0_1m = clampl(q0xm[j] + sigma * (xb0c[j] - xb0xm[j]), l0m[j]);
        float q0_2m = clampl(q0_1m + sigma * (xb1c[j] - xb1xm[j]), l0m[j]);
        float q1_1m = clampl(q1ym[j] + sigma * (xb0c[j] - xb0ym[j]), l1m[j]);
        float q1_2m = clampl(q1_1m + sigma * (xb1c[j] - xb1ym[j]), l1m[j]);
        float q2_1m  = (j == 0) ? q2_1_tm : q2n[j - 1];
        float l2m    = (j == 0) ? l2p     : l2c[j - 1];
        float xb1tm  = (j == 0) ? xb1_tm  : xb1c[j - 1];
        float q2_2m = clampl(q2_1m + sigma * (xb1c[j] - xb1tm), l2m);

        float div = (q0_2m - q02[j]) + (q1_2m - q12[j]) + (q2_2m - q22[j]);

        x2[j]  = x1v[j] - tau * (p2[j] + div);
        xb2[j] = x2[j] + theta * (x2[j] - x1v[j]);
    }

    const int off  = xbase + (gx * YDIM + gy) * TDIM + t0;
    const int qoff = qbase + (gx * YDIM + gy) * TDIM + t0;
    *(float4*)(pOut + off) = make_float4(p2[0], p2[1], p2[2], p2[3]);
    *(float4*)(xOut + off) = make_float4(x2[0], x2[1], x2[2], x2[3]);

    half4 hq0, hq1, hq2, hxb;
    hq0.x=(hreal)q02[0]; hq0.y=(hreal)q02[1]; hq0.z=(hreal)q02[2]; hq0.w=(hreal)q02[3];
    hq1.x=(hreal)q12[0]; hq1.y=(hreal)q12[1]; hq1.z=(hreal)q12[2]; hq1.w=(hreal)q12[3];
    hq2.x=(hreal)q22[0]; hq2.y=(hreal)q22[1]; hq2.z=(hreal)q22[2]; hq2.w=(hreal)q22[3];
    hxb.x=(hreal)xb2[0]; hxb.y=(hreal)xb2[1]; hxb.z=(hreal)xb2[2]; hxb.w=(hreal)xb2[3];
    *(half4*)(qOut + qoff)           = hq0;
    *(half4*)(qOut + qoff + VOL)     = hq1;
    *(half4*)(qOut + qoff + 2 * VOL) = hq2;
    *(half4*)(xbOut + off)           = hxb;
}

extern "C" void kernel_launch(void* const* d_in, const int* in_sizes, int n_in,
                              void* d_out, int out_size, void* d_ws, size_t ws_size,
                              hipStream_t stream) {
    const float* x   = (const float*)d_in[0];
    const float* lam = (const float*)d_in[1];
    float* out = (float*)d_out;
    float* ws  = (float*)d_ws;

    // ws layout: [pA|pB|xB] fp32 (3*NX floats) then fp16 region (12*NX halves)
    // total = 3*NX*4 + 12*NX*2 = 36*NX bytes = 29.5 MB
    float* pA  = ws;
    float* pB  = ws + (size_t)NX;
    float* xBb = ws + (size_t)2 * NX;
    float* xAb = out;   // parity: launch 23 (odd) writes A family -> x_48 in d_out
    hreal* hb  = (hreal*)(ws + (size_t)3 * NX);
    hreal* xbAh = hb;
    hreal* xbBh = hb + (size_t)NX;
    hreal* qAh  = hb + (size_t)2 * NX;
    hreal* qBh  = hb + (size_t)5 * NX;
    hreal* lamh = hb + (size_t)8 * NX;
    hreal* xnh  = hb + (size_t)11 * NX;

    const double s10 = 1.0 / (1.0 + exp(-10.0));
    const double L   = sqrt(13.0);
    float sigma  = (float)(s10 / L);
    float tau    = sigma;
    float theta  = (float)s10;
    float inv1ps = (float)(1.0 / (1.0 + s10 / L));

    init_kernel<<<(3 * NX + 255) / 256, 256, 0, stream>>>(
        x, lam, pA, xAb, xbAh, qAh, lamh, xnh);

    for (int j = 0; j < T_ITERS / 2; ++j) {
        const bool e = (j & 1) == 0;
        pd_step2<<<NBLK, 256, 0, stream>>>(
            xnh, lamh,
            e ? pA : pB,   e ? pB : pA,
            e ? xAb : xBb, e ? xBb : xAb,
            e ? xbAh : xbBh, e ? xbBh : xbAh,
            e ? qAh : qBh,  e ? qBh : qAh,
            sigma, inv1ps, tau, theta);
    }
}

// Round 6
// 351.953 us; speedup vs baseline: 23.9597x; 1.0099x over previous
//
#include <hip/hip_runtime.h>
#include <math.h>

// K=2 temporal fusion + fp16 storage (R4) + phase-0 load aggregation (R5):
// every global load issues before the first __syncthreads so the barrier's
// vmcnt(0) drain overlaps ALL load latency once, instead of 3 serialized
// chains. q2/lam2 t-minus values come from __shfl of sibling-lane registers.
#define XDIM 160
#define YDIM 160
#define TDIM 16
#define NB 2
#define T_ITERS 48
#define TILE 8
#define H1S (TILE + 2)    // 10: iter1 output region (dilate 1)
#define H2S (TILE + 4)    // 12: xbar_0 staging region (dilate 2)
#define TPT (XDIM / TILE) // 20 tiles per side

constexpr int VOL  = XDIM * YDIM * TDIM;  // 409600
constexpr int NX   = NB * VOL;            // 819200
constexpr int NBLK = NB * TPT * TPT;      // 800 blocks

typedef _Float16 hreal;
typedef _Float16 half4 __attribute__((ext_vector_type(4)));

__device__ __forceinline__ float clampl(float v, float l) {
    return fminf(fmaxf(v, -l), l);
}
__device__ __forceinline__ int wrap(int v) {
    return v < 0 ? v + XDIM : (v >= XDIM ? v - XDIM : v);
}

__global__ __launch_bounds__(256) void init_kernel(
    const float* __restrict__ x, const float* __restrict__ lam,
    float* __restrict__ pA, float* __restrict__ xA,
    hreal* __restrict__ xbAh, hreal* __restrict__ qAh,
    hreal* __restrict__ lamh, hreal* __restrict__ xnh)
{
    int i = blockIdx.x * blockDim.x + threadIdx.x;
    if (i < NX) {
        float v = x[i];
        pA[i] = v; xA[i] = v;
        xbAh[i] = (hreal)v;
        xnh[i]  = (hreal)v;
    }
    if (i < 3 * NX) {
        qAh[i]  = (hreal)0.f;
        lamh[i] = (hreal)lam[i];
    }
}

// All global state one line/t-quad needs for one PD iteration.
struct LineState {
    float4 P0, X0;
    half4 XN, Q0C, Q0XM, Q1C, Q1YM, Q2C, L0C, L0M, L1C, L1M, L2C;
};

__device__ __forceinline__ LineState load_line_state(
    const hreal* __restrict__ xnh, const hreal* __restrict__ lamh,
    const float* __restrict__ pIn, const float* __restrict__ xIn,
    const hreal* __restrict__ qIn, int b, int gx, int gy, int t0)
{
    const int gxm = wrap(gx - 1), gym = wrap(gy - 1);
    const int xbase = b * VOL, qbase = b * 3 * VOL;
    const int lineC  = (gx * YDIM + gy) * TDIM;
    const int lineXM = (gxm * YDIM + gy) * TDIM;
    const int lineYM = (gx * YDIM + gym) * TDIM;
    const int off = xbase + lineC + t0;
    LineState s;
    s.P0   = *(const float4*)(pIn + off);
    s.X0   = *(const float4*)(xIn + off);
    s.XN   = *(const half4*)(xnh + off);
    s.Q0C  = *(const half4*)(qIn + qbase + lineC + t0);
    s.Q0XM = *(const half4*)(qIn + qbase + lineXM + t0);
    s.Q1C  = *(const half4*)(qIn + qbase + VOL + lineC + t0);
    s.Q1YM = *(const half4*)(qIn + qbase + VOL + lineYM + t0);
    s.Q2C  = *(const half4*)(qIn + qbase + 2 * VOL + lineC + t0);
    s.L0C  = *(const half4*)(lamh + qbase + lineC + t0);
    s.L0M  = *(const half4*)(lamh + qbase + lineXM + t0);
    s.L1C  = *(const half4*)(lamh + qbase + VOL + lineC + t0);
    s.L1M  = *(const half4*)(lamh + qbase + VOL + lineYM + t0);
    s.L2C  = *(const half4*)(lamh + qbase + 2 * VOL + lineC + t0);
    return s;
}

// One PD iteration from pre-loaded state + LDS xbar_0; writes xbar_1 to LDS.
// t-minus values of q2/lam2 come from the sibling lane (4 lanes = 1 line).
__device__ __forceinline__ void compute_iter1(
    const LineState& S,
    const float* __restrict__ xb0, float* __restrict__ xb1,
    int hx1, int hy1, int t0, int dnSrc,
    float sigma, float inv1ps, float tau, float theta,
    float* pn, float* x1v, float* q0n, float* q1n, float* q2n,
    float* q0xm, float* q1ym,
    float* l0c, float* l1c, float* l2c, float* l0m, float* l1m, float* xnc)
{
    const int h2c  = ((hx1 + 1) * H2S + (hy1 + 1)) * TDIM;
    const int h2xp = ((hx1 + 2) * H2S + (hy1 + 1)) * TDIM;
    const int h2xm = ((hx1    ) * H2S + (hy1 + 1)) * TDIM;
    const int h2yp = ((hx1 + 1) * H2S + (hy1 + 2)) * TDIM;
    const int h2ym = ((hx1 + 1) * H2S + (hy1    )) * TDIM;

    const float4 XBC  = *(const float4*)(xb0 + h2c + t0);
    const float4 XBXP = *(const float4*)(xb0 + h2xp + t0);
    const float4 XBXM = *(const float4*)(xb0 + h2xm + t0);
    const float4 XBYP = *(const float4*)(xb0 + h2yp + t0);
    const float4 XBYM = *(const float4*)(xb0 + h2ym + t0);
    const float xb_tm = xb0[h2c + ((t0 + TDIM - 1) & (TDIM - 1))];
    const float xb_tp = xb0[h2c + ((t0 + 4) & (TDIM - 1))];

    float xbc[4]  = {XBC.x, XBC.y, XBC.z, XBC.w};
    float xbxp[4] = {XBXP.x, XBXP.y, XBXP.z, XBXP.w};
    float xbxm[4] = {XBXM.x, XBXM.y, XBXM.z, XBXM.w};
    float xbyp[4] = {XBYP.x, XBYP.y, XBYP.z, XBYP.w};
    float xbym[4] = {XBYM.x, XBYM.y, XBYM.z, XBYM.w};
    float pc[4]   = {S.P0.x, S.P0.y, S.P0.z, S.P0.w};
    float x0c[4]  = {S.X0.x, S.X0.y, S.X0.z, S.X0.w};
    float q0c[4]  = {(float)S.Q0C.x, (float)S.Q0C.y, (float)S.Q0C.z, (float)S.Q0C.w};
    float q1c[4]  = {(float)S.Q1C.x, (float)S.Q1C.y, (float)S.Q1C.z, (float)S.Q1C.w};
    float q2c[4]  = {(float)S.Q2C.x, (float)S.Q2C.y, (float)S.Q2C.z, (float)S.Q2C.w};

    xnc[0]=(float)S.XN.x; xnc[1]=(float)S.XN.y; xnc[2]=(float)S.XN.z; xnc[3]=(float)S.XN.w;
    q0xm[0]=(float)S.Q0XM.x; q0xm[1]=(float)S.Q0XM.y; q0xm[2]=(float)S.Q0XM.z; q0xm[3]=(float)S.Q0XM.w;
    q1ym[0]=(float)S.Q1YM.x; q1ym[1]=(float)S.Q1YM.y; q1ym[2]=(float)S.Q1YM.z; q1ym[3]=(float)S.Q1YM.w;
    l0c[0]=(float)S.L0C.x; l0c[1]=(float)S.L0C.y; l0c[2]=(float)S.L0C.z; l0c[3]=(float)S.L0C.w;
    l1c[0]=(float)S.L1C.x; l1c[1]=(float)S.L1C.y; l1c[2]=(float)S.L1C.z; l1c[3]=(float)S.L1C.w;
    l2c[0]=(float)S.L2C.x; l2c[1]=(float)S.L2C.y; l2c[2]=(float)S.L2C.z; l2c[3]=(float)S.L2C.w;
    l0m[0]=(float)S.L0M.x; l0m[1]=(float)S.L0M.y; l0m[2]=(float)S.L0M.z; l0m[3]=(float)S.L0M.w;
    l1m[0]=(float)S.L1M.x; l1m[1]=(float)S.L1M.y; l1m[2]=(float)S.L1M.z; l1m[3]=(float)S.L1M.w;

    // t0-1 values from sibling lane's registers (bit-identical to a load)
    const float Q2TM = __shfl(q2c[3], dnSrc, 64);
    const float L2TM = __shfl(l2c[3], dnSrc, 64);

    float xbn[4];
    #pragma unroll
    for (int j = 0; j < 4; ++j) {
        pn[j] = (pc[j] + sigma * (xbc[j] - xnc[j])) * inv1ps;

        float gx1 = xbxp[j] - xbc[j];
        float gy1 = xbyp[j] - xbc[j];
        float gt1 = ((j < 3) ? xbc[j + 1] : xb_tp) - xbc[j];

        q0n[j] = clampl(q0c[j] + sigma * gx1, l0c[j]);
        q1n[j] = clampl(q1c[j] + sigma * gy1, l1c[j]);
        q2n[j] = clampl(q2c[j] + sigma * gt1, l2c[j]);

        float q0m = clampl(q0xm[j] + sigma * (xbc[j] - xbxm[j]), l0m[j]);
        float q1m = clampl(q1ym[j] + sigma * (xbc[j] - xbym[j]), l1m[j]);
        float gtm    = xbc[j] - ((j == 0) ? xb_tm : xbc[j - 1]);
        float q2prev = (j == 0) ? Q2TM : q2c[j - 1];
        float l2prev = (j == 0) ? L2TM : l2c[j - 1];
        float q2m = clampl(q2prev + sigma * gtm, l2prev);

        float div = (q0m - q0n[j]) + (q1m - q1n[j]) + (q2m - q2n[j]);

        x1v[j] = x0c[j] - tau * (pn[j] + div);
        xbn[j] = x1v[j] + theta * (x1v[j] - x0c[j]);
    }

    const int h1c = (hx1 * H1S + hy1) * TDIM;
    *(float4*)(xb1 + h1c + t0) = make_float4(xbn[0], xbn[1], xbn[2], xbn[3]);
}

// Two fused PD iterations per launch; all global loads issue in phase 0.
__global__ __launch_bounds__(256, 3) void pd_step2(
    const hreal* __restrict__ xnh, const hreal* __restrict__ lamh,
    const float* __restrict__ pIn, float* __restrict__ pOut,
    const float* __restrict__ xIn, float* __restrict__ xOut,
    const hreal* __restrict__ xbIn, hreal* __restrict__ xbOut,
    const hreal* __restrict__ qIn, hreal* __restrict__ qOut,
    float sigma, float inv1ps, float tau, float theta)
{
    __shared__ float xb0[H2S * H2S * TDIM];  // 9.2 KB
    __shared__ float xb1[H1S * H1S * TDIM];  // 6.4 KB

    const int tid = threadIdx.x;
    const int b    = blockIdx.x / (TPT * TPT);
    const int rem  = blockIdx.x % (TPT * TPT);
    const int x0g  = (rem / TPT) * TILE;
    const int y0g  = (rem % TPT) * TILE;
    const int xbase = b * VOL, qbase = b * 3 * VOL;

    // ---- phase 0a: stage xbar_0 (fp16 -> fp32) over 12x12 halo into LDS ----
    for (int s = tid; s < H2S * H2S * 4; s += 256) {
        int quad = s & 3, hl = s >> 2;
        int gx = wrap(x0g + hl / H2S - 2);
        int gy = wrap(y0g + hl % H2S - 2);
        const half4 H = *(const half4*)(xbIn + xbase + (gx * YDIM + gy) * TDIM + quad * 4);
        *(float4*)(xb0 + hl * TDIM + quad * 4) =
            make_float4((float)H.x, (float)H.y, (float)H.z, (float)H.w);
    }

    // ---- phase 0b: prefetch halo-task state (tid<144) ----
    const bool isHalo = tid < 144;
    int hhx = 0, hhy = 0, hquad = tid & 3;
    LineState Sh;
    if (isHalo) {
        int hl = tid >> 2;
        if (hl < 10)      { hhx = 0; hhy = hl; }
        else if (hl < 20) { hhx = 9; hhy = hl - 10; }
        else              { int r = hl - 20; hhx = 1 + (r >> 1); hhy = (r & 1) * 9; }
        int ggx = wrap(x0g + hhx - 1), ggy = wrap(y0g + hhy - 1);
        Sh = load_line_state(xnh, lamh, pIn, xIn, qIn, b, ggx, ggy, hquad * 4);
    }

    // ---- phase 0c: prefetch center-task state ----
    const int t0 = (tid & 3) * 4;
    const int cline = tid >> 2;
    const int cx = cline >> 3, cy = cline & 7;
    const int hx1 = cx + 1, hy1 = cy + 1;
    const int gx = x0g + cx, gy = y0g + cy;
    const LineState Sc = load_line_state(xnh, lamh, pIn, xIn, qIn, b, gx, gy, t0);

    const int lane  = tid & 63;
    const int dnSrc = (lane & 60) | ((lane + 3) & 3);

    __syncthreads();   // drains all loads once, overlapped

    // ---- phase 1: iter1 on halo ring, then center (pure reg/LDS compute) ----
    if (isHalo) {
        float d0[4],d1[4],d2[4],d3[4],d4[4],d5[4],d6[4],
              d7[4],d8[4],d9[4],d10[4],d11[4],d12[4];
        compute_iter1(Sh, xb0, xb1, hhx, hhy, hquad * 4, dnSrc,
                      sigma, inv1ps, tau, theta,
                      d0,d1,d2,d3,d4,d5,d6,d7,d8,d9,d10,d11,d12);
    }

    float pn[4], x1v[4], q0n[4], q1n[4], q2n[4], q0xm[4], q1ym[4];
    float l0c[4], l1c[4], l2c[4], l0m[4], l1m[4], xnc[4];
    compute_iter1(Sc, xb0, xb1, hx1, hy1, t0, dnSrc,
                  sigma, inv1ps, tau, theta,
                  pn, x1v, q0n, q1n, q2n, q0xm, q1ym,
                  l0c, l1c, l2c, l0m, l1m, xnc);
    __syncthreads();

    // ---- phase 2: iter2 on center from LDS xbar_1 + registers ----
    const int h1c  = (hx1 * H1S + hy1) * TDIM;
    const int h1xp = ((hx1 + 1) * H1S + hy1) * TDIM;
    const int h1xm = ((hx1 - 1) * H1S + hy1) * TDIM;
    const int h1yp = (hx1 * H1S + (hy1 + 1)) * TDIM;
    const int h1ym = (hx1 * H1S + (hy1 - 1)) * TDIM;
    const float4 B1C  = *(const float4*)(xb1 + h1c + t0);
    const float4 B1XP = *(const float4*)(xb1 + h1xp + t0);
    const float4 B1XM = *(const float4*)(xb1 + h1xm + t0);
    const float4 B1YP = *(const float4*)(xb1 + h1yp + t0);
    const float4 B1YM = *(const float4*)(xb1 + h1ym + t0);
    const float xb1_tm = xb1[h1c + ((t0 + TDIM - 1) & (TDIM - 1))];
    const float xb1_tp = xb1[h1c + ((t0 + 4) & (TDIM - 1))];

    const int h2c  = ((hx1 + 1) * H2S + (hy1 + 1)) * TDIM;
    const int h2xm = ((hx1    ) * H2S + (hy1 + 1)) * TDIM;
    const int h2ym = ((hx1 + 1) * H2S + (hy1    )) * TDIM;
    const float4 B0C  = *(const float4*)(xb0 + h2c + t0);
    const float4 B0XM = *(const float4*)(xb0 + h2xm + t0);
    const float4 B0YM = *(const float4*)(xb0 + h2ym + t0);

    float xb1c[4]  = {B1C.x, B1C.y, B1C.z, B1C.w};
    float xb1xp[4] = {B1XP.x, B1XP.y, B1XP.z, B1XP.w};
    float xb1xm[4] = {B1XM.x, B1XM.y, B1XM.z, B1XM.w};
    float xb1yp[4] = {B1YP.x, B1YP.y, B1YP.z, B1YP.w};
    float xb1ym[4] = {B1YM.x, B1YM.y, B1YM.z, B1YM.w};
    float xb0c[4]  = {B0C.x, B0C.y, B0C.z, B0C.w};
    float xb0xm[4] = {B0XM.x, B0XM.y, B0XM.z, B0XM.w};
    float xb0ym[4] = {B0YM.x, B0YM.y, B0YM.z, B0YM.w};

    const float q2_1_tm = __shfl(q2n[3], dnSrc, 64);
    const float l2p     = __shfl(l2c[3], dnSrc, 64);

    float p2[4], q02[4], q12[4], q22[4], x2[4], xb2[4];
    #pragma unroll
    for (int j = 0; j < 4; ++j) {
        p2[j] = (pn[j] + sigma * (xb1c[j] - xnc[j])) * inv1ps;

        float gx1 = xb1xp[j] - xb1c[j];
        float gy1 = xb1yp[j] - xb1c[j];
        float gt1 = ((j < 3) ? xb1c[j + 1] : xb1_tp) - xb1c[j];
        q02[j] = clampl(q0n[j] + sigma * gx1, l0c[j]);
        q12[j] = clampl(q1n[j] + sigma * gy1, l1c[j]);
        q22[j] = clampl(q2n[j] + sigma * gt1, l2c[j]);

        float q0_1m = clampl(q0xm[j] + sigma * (xb0c[j] - xb0xm[j]), l0m[j]);
        float q0_2m = clampl(q0_1m + sigma * (xb1c[j] - xb1xm[j]), l0m[j]);
        float q1_1m = clampl(q1ym[j] + sigma * (xb0c[j] - xb0ym[j]), l1m[j]);
        float q1_2m = clampl(q1_1m + sigma * (xb1c[j] - xb1ym[j]), l1m[j]);
        float q2_1m  = (j == 0) ? q2_1_tm : q2n[j - 1];
        float l2m    = (j == 0) ? l2p     : l2c[j - 1];
        float xb1tm  = (j == 0) ? xb1_tm  : xb1c[j - 1];
        float q2_2m = clampl(q2_1m + sigma * (xb1c[j] - xb1tm), l2m);

        float div = (q0_2m - q02[j]) + (q1_2m - q12[j]) + (q2_2m - q22[j]);

        x2[j]  = x1v[j] - tau * (p2[j] + div);
        xb2[j] = x2[j] + theta * (x2[j] - x1v[j]);
    }

    const int off  = xbase + (gx * YDIM + gy) * TDIM + t0;
    const int qoff = qbase + (gx * YDIM + gy) * TDIM + t0;
    *(float4*)(pOut + off) = make_float4(p2[0], p2[1], p2[2], p2[3]);
    *(float4*)(xOut + off) = make_float4(x2[0], x2[1], x2[2], x2[3]);

    half4 hq0, hq1, hq2, hxb;
    hq0.x=(hreal)q02[0]; hq0.y=(hreal)q02[1]; hq0.z=(hreal)q02[2]; hq0.w=(hreal)q02[3];
    hq1.x=(hreal)q12[0]; hq1.y=(hreal)q12[1]; hq1.z=(hreal)q12[2]; hq1.w=(hreal)q12[3];
    hq2.x=(hreal)q22[0]; hq2.y=(hreal)q22[1]; hq2.z=(hreal)q22[2]; hq2.w=(hreal)q22[3];
    hxb.x=(hreal)xb2[0]; hxb.y=(hreal)xb2[1]; hxb.z=(hreal)xb2[2]; hxb.w=(hreal)xb2[3];
    *(half4*)(qOut + qoff)           = hq0;
    *(half4*)(qOut + qoff + VOL)     = hq1;
    *(half4*)(qOut + qoff + 2 * VOL) = hq2;
    *(half4*)(xbOut + off)           = hxb;
}

extern "C" void kernel_launch(void* const* d_in, const int* in_sizes, int n_in,
                              void* d_out, int out_size, void* d_ws, size_t ws_size,
                              hipStream_t stream) {
    const float* x   = (const float*)d_in[0];
    const float* lam = (const float*)d_in[1];
    float* out = (float*)d_out;
    float* ws  = (float*)d_ws;

    // ws layout: [pA|pB|xB] fp32 (3*NX floats) then fp16 region (12*NX halves)
    float* pA  = ws;
    float* pB  = ws + (size_t)NX;
    float* xBb = ws + (size_t)2 * NX;
    float* xAb = out;   // parity: launch 23 (odd) writes A family -> x_48 in d_out
    hreal* hb  = (hreal*)(ws + (size_t)3 * NX);
    hreal* xbAh = hb;
    hreal* xbBh = hb + (size_t)NX;
    hreal* qAh  = hb + (size_t)2 * NX;
    hreal* qBh  = hb + (size_t)5 * NX;
    hreal* lamh = hb + (size_t)8 * NX;
    hreal* xnh  = hb + (size_t)11 * NX;

    const double s10 = 1.0 / (1.0 + exp(-10.0));
    const double L   = sqrt(13.0);
    float sigma  = (float)(s10 / L);
    float tau    = sigma;
    float theta  = (float)s10;
    float inv1ps = (float)(1.0 / (1.0 + s10 / L));

    init_kernel<<<(3 * NX + 255) / 256, 256, 0, stream>>>(
        x, lam, pA, xAb, xbAh, qAh, lamh, xnh);

    for (int j = 0; j < T_ITERS / 2; ++j) {
        const bool e = (j & 1) == 0;
        pd_step2<<<NBLK, 256, 0, stream>>>(
            xnh, lamh,
            e ? pA : pB,   e ? pB : pA,
            e ? xAb : xBb, e ? xBb : xAb,
            e ? xbAh : xbBh, e ? xbBh : xbAh,
            e ? qAh : qBh,  e ? qBh : qAh,
            sigma, inv1ps, tau, theta);
    }
}

// Round 7
// 298.348 us; speedup vs baseline: 28.2647x; 1.1797x over previous
//
#include <hip/hip_runtime.h>
#include <math.h>

// K=4 temporal fusion: 12 launches of a 4-iteration fused primal-dual step.
// Pyramid per block (center TILE=10): level-1 on 16^2, ..., level-4 on 10^2.
// Intermediate xbar in fp32 LDS (18^2 lines, in-place per level); q0/q1 in
// fp32 LDS (17x16 / 16x17) so backward-neighbor q is READ (post-barrier)
// instead of recomputed. q2 / T-direction handled in registers + __shfl
// (4 lanes = 4 T-quads of one line). Global state fp16 (xbar,q,lam,xn),
// fp32 (p,x); fp16 rounding once per 4 iterations.
#define XDIM 160
#define YDIM 160
#define TDIM 16
#define NB 2
#define T_ITERS 48
#define TILE 10
#define R1S 16            // level-1 region side (TILE+6)
#define R0S 18            // xbar staging side (TILE+8)
#define TPT (XDIM / TILE) // 16 tiles per side

constexpr int VOL  = XDIM * YDIM * TDIM;  // 409600
constexpr int NX   = NB * VOL;            // 819200
constexpr int NBLK = NB * TPT * TPT;      // 512 blocks

typedef _Float16 hreal;
typedef _Float16 half4 __attribute__((ext_vector_type(4)));

__device__ __forceinline__ float clampl(float v, float l) {
    return fminf(fmaxf(v, -l), l);
}
__device__ __forceinline__ int wrap(int v) {  // v in [-4, 164)
    return v < 0 ? v + XDIM : (v >= XDIM ? v - XDIM : v);
}
__device__ __forceinline__ void ld4(const float* p, float* d) {
    float4 v = *(const float4*)p;
    d[0] = v.x; d[1] = v.y; d[2] = v.z; d[3] = v.w;
}
__device__ __forceinline__ void st4(float* p, const float* s) {
    *(float4*)p = make_float4(s[0], s[1], s[2], s[3]);
}
__device__ __forceinline__ void h2f4(const hreal* p, float* d) {
    half4 v = *(const half4*)p;
    d[0] = (float)v.x; d[1] = (float)v.y; d[2] = (float)v.z; d[3] = (float)v.w;
}

__global__ __launch_bounds__(256) void init_kernel(
    const float* __restrict__ x, const float* __restrict__ lam,
    float* __restrict__ pA, float* __restrict__ xA,
    hreal* __restrict__ xbAh, hreal* __restrict__ qAh,
    hreal* __restrict__ lamh, hreal* __restrict__ xnh)
{
    int i = blockIdx.x * blockDim.x + threadIdx.x;
    if (i < NX) {
        float v = x[i];
        pA[i] = v; xA[i] = v;
        xbAh[i] = (hreal)v;
        xnh[i]  = (hreal)v;
    }
    if (i < 3 * NX) {
        qAh[i]  = (hreal)0.f;
        lamh[i] = (hreal)lam[i];
    }
}

__global__ __launch_bounds__(256, 2) void pd_step4(
    const hreal* __restrict__ xnh, const hreal* __restrict__ lamh,
    const float* __restrict__ pIn, float* __restrict__ pOut,
    const float* __restrict__ xIn, float* __restrict__ xOut,
    const hreal* __restrict__ xbIn, hreal* __restrict__ xbOut,
    const hreal* __restrict__ qIn, hreal* __restrict__ qOut,
    float sigma, float inv1ps, float tau, float theta)
{
    __shared__ float xbS[R0S * R0S * TDIM];        // 18*18*16 fp32 = 20.25 KB
    __shared__ float q0S[(R1S + 1) * R1S * TDIM];  // 17*16*16, idx (lx+1)*16+ly
    __shared__ float q1S[R1S * (R1S + 1) * TDIM];  // 16*17*16, idx lx*17+(ly+1)

    const int tid = threadIdx.x;
    const int b   = blockIdx.x / (TPT * TPT);
    const int rem = blockIdx.x % (TPT * TPT);
    const int X0  = (rem / TPT) * TILE;
    const int Y0  = (rem % TPT) * TILE;
    const int xbase = b * VOL, qbase = b * 3 * VOL;

    const int qd = tid & 3, t0 = qd * 4;
    const int lane  = tid & 63;
    const int upSrc = (lane & 60) | ((lane + 1) & 3);
    const int dnSrc = (lane & 60) | ((lane + 3) & 3);

    // ---- phase 0: stage xbar_0 / q0_0 / q1_0 into LDS ----
    for (int s = tid; s < R0S * R0S * 4; s += 256) {
        int sq = s & 3, ln = s >> 2;
        int rx = ln / R0S, ry = ln % R0S;
        int gx = wrap(X0 - 4 + rx), gy = wrap(Y0 - 4 + ry);
        float v[4];
        h2f4(xbIn + xbase + (gx * YDIM + gy) * TDIM + sq * 4, v);
        st4(xbS + ln * TDIM + sq * 4, v);
    }
    for (int s = tid; s < 17 * 16 * 4; s += 256) {
        int sq = s & 3, ln = s >> 2;
        int sx = ln / 16, sy = ln % 16;
        int gx = wrap(X0 - 4 + sx), gy = wrap(Y0 - 3 + sy);
        float v[4];
        h2f4(qIn + qbase + (gx * YDIM + gy) * TDIM + sq * 4, v);
        st4(q0S + ln * TDIM + sq * 4, v);
    }
    for (int s = tid; s < 16 * 17 * 4; s += 256) {
        int sq = s & 3, ln = s >> 2;
        int sx = ln / 17, sy = ln % 17;
        int gx = wrap(X0 - 3 + sx), gy = wrap(Y0 - 4 + sy);
        float v[4];
        h2f4(qIn + qbase + VOL + (gx * YDIM + gy) * TDIM + sq * 4, v);
        st4(q1S + ln * TDIM + sq * 4, v);
    }

    // ---- phase 0b: per-slot persistent state (4 slots/thread) ----
    float p[4][4], xv[4][4], xb[4][4], q0[4][4], q1[4][4], q2[4][4];
    half4 XNr[4], L0r[4], L1r[4], L2r[4];
    #pragma unroll
    for (int m = 0; m < 4; ++m) {
        int line = 64 * m + (tid >> 2);
        int lx = line >> 4, ly = line & 15;
        int gx = wrap(X0 - 3 + lx), gy = wrap(Y0 - 3 + ly);
        int off  = xbase + (gx * YDIM + gy) * TDIM + t0;
        int qoff = qbase + (gx * YDIM + gy) * TDIM + t0;
        ld4(pIn + off, p[m]);
        ld4(xIn + off, xv[m]);
        h2f4(xbIn + off, xb[m]);               // == LDS copy (same cvt)
        h2f4(qIn + qoff + 2 * VOL, q2[m]);
        XNr[m] = *(const half4*)(xnh + off);
        L0r[m] = *(const half4*)(lamh + qoff);
        L1r[m] = *(const half4*)(lamh + qoff + VOL);
        L2r[m] = *(const half4*)(lamh + qoff + 2 * VOL);
    }

    // ring lambdas (level-1 backward q rings at lx=-1 / ly=-1)
    half4 LRr;
    if (tid < 64) {
        int rly = tid >> 2;
        LRr = *(const half4*)(lamh + qbase +
              (wrap(X0 - 4) * YDIM + wrap(Y0 - 3 + rly)) * TDIM + t0);
    } else if (tid < 128) {
        int rlx = (tid - 64) >> 2;
        LRr = *(const half4*)(lamh + qbase + VOL +
              (wrap(X0 - 3 + rlx) * YDIM + wrap(Y0 - 4)) * TDIM + t0);
    }

    __syncthreads();

    // ---- level loop: k = 1..4 ----
    #pragma unroll
    for (int k = 1; k <= 4; ++k) {
        const int lo = k - 1, hi = 17 - k;

        // ===== phase B: update p, q (own); write q0,q1 to LDS =====
        if (k == 1) {
            // level-1 backward rings (outside R1): q at lx=-1 / ly=-1
            if (tid < 64) {
                int rly = tid >> 2;
                float qr[4], xbc[4], xpx[4];
                ld4(q0S + (0 * R1S + rly) * TDIM + t0, qr);
                ld4(xbS + (0 * R0S + (rly + 1)) * TDIM + t0, xbc);
                ld4(xbS + (1 * R0S + (rly + 1)) * TDIM + t0, xpx);
                #pragma unroll
                for (int j = 0; j < 4; ++j)
                    qr[j] = clampl(qr[j] + sigma * (xpx[j] - xbc[j]), (float)LRr[j]);
                st4(q0S + (0 * R1S + rly) * TDIM + t0, qr);
            } else if (tid < 128) {
                int rlx = (tid - 64) >> 2;
                float qr[4], xbc[4], xpy[4];
                ld4(q1S + (rlx * 17 + 0) * TDIM + t0, qr);
                ld4(xbS + ((rlx + 1) * R0S + 0) * TDIM + t0, xbc);
                ld4(xbS + ((rlx + 1) * R0S + 1) * TDIM + t0, xpy);
                #pragma unroll
                for (int j = 0; j < 4; ++j)
                    qr[j] = clampl(qr[j] + sigma * (xpy[j] - xbc[j]), (float)LRr[j]);
                st4(q1S + (rlx * 17 + 0) * TDIM + t0, qr);
            }
        }

        #pragma unroll
        for (int m = 0; m < 4; ++m) {
            int line = 64 * m + (tid >> 2);
            int lx = line >> 4, ly = line & 15;
            bool inX = (lx >= lo && lx < hi), inY = (ly >= lo && ly < hi);
            bool aq0 = inY && (lx >= lo - 1) && (lx < hi);
            bool aq1 = inX && (ly >= lo - 1) && (ly < hi);
            bool ax  = inX && inY;

            if (k == 1) {   // own q0,q1 from staged LDS (== global cvt)
                ld4(q0S + ((lx + 1) * R1S + ly) * TDIM + t0, q0[m]);
                ld4(q1S + (lx * 17 + (ly + 1)) * TDIM + t0, q1[m]);
            }
            if (aq0) {
                float xpx[4];
                ld4(xbS + ((lx + 2) * R0S + (ly + 1)) * TDIM + t0, xpx);
                #pragma unroll
                for (int j = 0; j < 4; ++j)
                    q0[m][j] = clampl(q0[m][j] + sigma * (xpx[j] - xb[m][j]),
                                      (float)L0r[m][j]);
                st4(q0S + ((lx + 1) * R1S + ly) * TDIM + t0, q0[m]);
            }
            if (aq1) {
                float xpy[4];
                ld4(xbS + ((lx + 1) * R0S + (ly + 2)) * TDIM + t0, xpy);
                #pragma unroll
                for (int j = 0; j < 4; ++j)
                    q1[m][j] = clampl(q1[m][j] + sigma * (xpy[j] - xb[m][j]),
                                      (float)L1r[m][j]);
                st4(q1S + (lx * 17 + (ly + 1)) * TDIM + t0, q1[m]);
            }
            if (ax) {
                float xb_tp = __shfl(xb[m][0], upSrc, 64);   // xbar at t0+4
                #pragma unroll
                for (int j = 0; j < 4; ++j) {
                    float gt = ((j < 3) ? xb[m][j + 1] : xb_tp) - xb[m][j];
                    q2[m][j] = clampl(q2[m][j] + sigma * gt, (float)L2r[m][j]);
                    p[m][j]  = (p[m][j] + sigma * (xb[m][j] - (float)XNr[m][j]))
                               * inv1ps;
                }
            }
        }
        __syncthreads();

        // ===== phase C: read backward q (new) from LDS; update x, xbar =====
        #pragma unroll
        for (int m = 0; m < 4; ++m) {
            int line = 64 * m + (tid >> 2);
            int lx = line >> 4, ly = line & 15;
            bool ax = (lx >= lo && lx < hi && ly >= lo && ly < hi);
            if (ax) {
                float q0b[4], q1b[4];
                ld4(q0S + (lx * R1S + ly) * TDIM + t0, q0b);       // (lx-1,ly)
                ld4(q1S + (lx * 17 + ly) * TDIM + t0, q1b);        // (lx,ly-1)
                float q2tm = __shfl(q2[m][3], dnSrc, 64);          // new, t0-1
                #pragma unroll
                for (int j = 0; j < 4; ++j) {
                    float q2p = (j == 0) ? q2tm : q2[m][j - 1];
                    float div = (q0b[j] - q0[m][j]) + (q1b[j] - q1[m][j])
                              + (q2p - q2[m][j]);
                    float xnew = xv[m][j] - tau * (p[m][j] + div);
                    xb[m][j] = xnew + theta * (xnew - xv[m][j]);
                    xv[m][j] = xnew;
                }
                if (k < 4)
                    st4(xbS + ((lx + 1) * R0S + (ly + 1)) * TDIM + t0, xb[m]);
            }
        }
        if (k < 4) __syncthreads();
    }

    // ---- output: center 10x10 lines ----
    #pragma unroll
    for (int m = 0; m < 4; ++m) {
        int line = 64 * m + (tid >> 2);
        int lx = line >> 4, ly = line & 15;
        if (lx >= 3 && lx < 13 && ly >= 3 && ly < 13) {
            int gx = X0 + lx - 3, gy = Y0 + ly - 3;
            int off  = xbase + (gx * YDIM + gy) * TDIM + t0;
            int qoff = qbase + (gx * YDIM + gy) * TDIM + t0;
            st4(pOut + off, p[m]);
            st4(xOut + off, xv[m]);
            half4 h;
            h.x = (hreal)xb[m][0]; h.y = (hreal)xb[m][1];
            h.z = (hreal)xb[m][2]; h.w = (hreal)xb[m][3];
            *(half4*)(xbOut + off) = h;
            h.x = (hreal)q0[m][0]; h.y = (hreal)q0[m][1];
            h.z = (hreal)q0[m][2]; h.w = (hreal)q0[m][3];
            *(half4*)(qOut + qoff) = h;
            h.x = (hreal)q1[m][0]; h.y = (hreal)q1[m][1];
            h.z = (hreal)q1[m][2]; h.w = (hreal)q1[m][3];
            *(half4*)(qOut + qoff + VOL) = h;
            h.x = (hreal)q2[m][0]; h.y = (hreal)q2[m][1];
            h.z = (hreal)q2[m][2]; h.w = (hreal)q2[m][3];
            *(half4*)(qOut + qoff + 2 * VOL) = h;
        }
    }
}

extern "C" void kernel_launch(void* const* d_in, const int* in_sizes, int n_in,
                              void* d_out, int out_size, void* d_ws, size_t ws_size,
                              hipStream_t stream) {
    const float* x   = (const float*)d_in[0];
    const float* lam = (const float*)d_in[1];
    float* out = (float*)d_out;
    float* ws  = (float*)d_ws;

    // ws: [pA|pB|xB] fp32 (3*NX floats) then fp16 region (12*NX halves)
    float* pA  = ws;
    float* pB  = ws + (size_t)NX;
    float* xBb = ws + (size_t)2 * NX;
    float* xAb = out;   // 12 launches: final (odd j) writes A family -> d_out
    hreal* hb  = (hreal*)(ws + (size_t)3 * NX);
    hreal* xbAh = hb;
    hreal* xbBh = hb + (size_t)NX;
    hreal* qAh  = hb + (size_t)2 * NX;
    hreal* qBh  = hb + (size_t)5 * NX;
    hreal* lamh = hb + (size_t)8 * NX;
    hreal* xnh  = hb + (size_t)11 * NX;

    const double s10 = 1.0 / (1.0 + exp(-10.0));
    const double L   = sqrt(13.0);
    float sigma  = (float)(s10 / L);
    float tau    = sigma;
    float theta  = (float)s10;
    float inv1ps = (float)(1.0 / (1.0 + s10 / L));

    init_kernel<<<(3 * NX + 255) / 256, 256, 0, stream>>>(
        x, lam, pA, xAb, xbAh, qAh, lamh, xnh);

    for (int j = 0; j < T_ITERS / 4; ++j) {   // 12 launches
        const bool e = (j & 1) == 0;
        pd_step4<<<NBLK, 256, 0, stream>>>(
            xnh, lamh,
            e ? pA : pB,   e ? pB : pA,
            e ? xAb : xBb, e ? xBb : xAb,
            e ? xbAh : xbBh, e ? xbBh : xbAh,
            e ? qAh : qBh,  e ? qBh : qAh,
            sigma, inv1ps, tau, theta);
    }
}

// Round 8
// 252.192 us; speedup vs baseline: 33.4377x; 1.1830x over previous
//
#include <hip/hip_runtime.h>
#include <math.h>

// K=4 temporal fusion, 12 launches. R7: 512-thread blocks, 2 slots/thread
// (was 256x4) -> 16 waves/CU instead of 8 at the same 512-block grid; math
// bit-identical to R6 (fp32 LDS exchange; fp16 global rounding per 4 iters).
#define XDIM 160
#define YDIM 160
#define TDIM 16
#define NB 2
#define T_ITERS 48
#define TILE 10
#define R1S 16            // level-1 region side (TILE+6)
#define R0S 18            // xbar staging side (TILE+8)
#define TPT (XDIM / TILE) // 16 tiles per side
#define NTHR 512

constexpr int VOL  = XDIM * YDIM * TDIM;  // 409600
constexpr int NX   = NB * VOL;            // 819200
constexpr int NBLK = NB * TPT * TPT;      // 512 blocks

typedef _Float16 hreal;
typedef _Float16 half4 __attribute__((ext_vector_type(4)));

__device__ __forceinline__ float clampl(float v, float l) {
    return fminf(fmaxf(v, -l), l);
}
__device__ __forceinline__ int wrap(int v) {  // v in [-4, 164)
    return v < 0 ? v + XDIM : (v >= XDIM ? v - XDIM : v);
}
__device__ __forceinline__ void ld4(const float* p, float* d) {
    float4 v = *(const float4*)p;
    d[0] = v.x; d[1] = v.y; d[2] = v.z; d[3] = v.w;
}
__device__ __forceinline__ void st4(float* p, const float* s) {
    *(float4*)p = make_float4(s[0], s[1], s[2], s[3]);
}
__device__ __forceinline__ void h2f4(const hreal* p, float* d) {
    half4 v = *(const half4*)p;
    d[0] = (float)v.x; d[1] = (float)v.y; d[2] = (float)v.z; d[3] = (float)v.w;
}

__global__ __launch_bounds__(256) void init_kernel(
    const float* __restrict__ x, const float* __restrict__ lam,
    float* __restrict__ pA, float* __restrict__ xA,
    hreal* __restrict__ xbAh, hreal* __restrict__ qAh,
    hreal* __restrict__ lamh, hreal* __restrict__ xnh)
{
    int i = blockIdx.x * blockDim.x + threadIdx.x;
    if (i < NX) {
        float v = x[i];
        pA[i] = v; xA[i] = v;
        xbAh[i] = (hreal)v;
        xnh[i]  = (hreal)v;
    }
    if (i < 3 * NX) {
        qAh[i]  = (hreal)0.f;
        lamh[i] = (hreal)lam[i];
    }
}

__global__ __launch_bounds__(NTHR, 4) void pd_step4(
    const hreal* __restrict__ xnh, const hreal* __restrict__ lamh,
    const float* __restrict__ pIn, float* __restrict__ pOut,
    const float* __restrict__ xIn, float* __restrict__ xOut,
    const hreal* __restrict__ xbIn, hreal* __restrict__ xbOut,
    const hreal* __restrict__ qIn, hreal* __restrict__ qOut,
    float sigma, float inv1ps, float tau, float theta)
{
    __shared__ float xbS[R0S * R0S * TDIM];        // 18*18*16 fp32 = 20.25 KB
    __shared__ float q0S[(R1S + 1) * R1S * TDIM];  // 17*16*16, idx (lx+1)*16+ly
    __shared__ float q1S[R1S * (R1S + 1) * TDIM];  // 16*17*16, idx lx*17+(ly+1)

    const int tid = threadIdx.x;
    const int b   = blockIdx.x / (TPT * TPT);
    const int rem = blockIdx.x % (TPT * TPT);
    const int X0  = (rem / TPT) * TILE;
    const int Y0  = (rem % TPT) * TILE;
    const int xbase = b * VOL, qbase = b * 3 * VOL;

    const int qd = tid & 3, t0 = qd * 4;
    const int lane  = tid & 63;
    const int upSrc = (lane & 60) | ((lane + 1) & 3);
    const int dnSrc = (lane & 60) | ((lane + 3) & 3);

    // ---- phase 0: stage xbar_0 / q0_0 / q1_0 into LDS ----
    for (int s = tid; s < R0S * R0S * 4; s += NTHR) {
        int sq = s & 3, ln = s >> 2;
        int rx = ln / R0S, ry = ln % R0S;
        int gx = wrap(X0 - 4 + rx), gy = wrap(Y0 - 4 + ry);
        float v[4];
        h2f4(xbIn + xbase + (gx * YDIM + gy) * TDIM + sq * 4, v);
        st4(xbS + ln * TDIM + sq * 4, v);
    }
    for (int s = tid; s < 17 * 16 * 4; s += NTHR) {
        int sq = s & 3, ln = s >> 2;
        int sx = ln / 16, sy = ln % 16;
        int gx = wrap(X0 - 4 + sx), gy = wrap(Y0 - 3 + sy);
        float v[4];
        h2f4(qIn + qbase + (gx * YDIM + gy) * TDIM + sq * 4, v);
        st4(q0S + ln * TDIM + sq * 4, v);
    }
    for (int s = tid; s < 16 * 17 * 4; s += NTHR) {
        int sq = s & 3, ln = s >> 2;
        int sx = ln / 17, sy = ln % 17;
        int gx = wrap(X0 - 3 + sx), gy = wrap(Y0 - 4 + sy);
        float v[4];
        h2f4(qIn + qbase + VOL + (gx * YDIM + gy) * TDIM + sq * 4, v);
        st4(q1S + ln * TDIM + sq * 4, v);
    }

    // ---- phase 0b: per-slot persistent state (2 slots/thread) ----
    float p[2][4], xv[2][4], xb[2][4], q0[2][4], q1[2][4], q2[2][4];
    half4 XNr[2], L0r[2], L1r[2], L2r[2];
    #pragma unroll
    for (int m = 0; m < 2; ++m) {
        int line = 128 * m + (tid >> 2);
        int lx = line >> 4, ly = line & 15;
        int gx = wrap(X0 - 3 + lx), gy = wrap(Y0 - 3 + ly);
        int off  = xbase + (gx * YDIM + gy) * TDIM + t0;
        int qoff = qbase + (gx * YDIM + gy) * TDIM + t0;
        ld4(pIn + off, p[m]);
        ld4(xIn + off, xv[m]);
        h2f4(qIn + qoff + 2 * VOL, q2[m]);
        XNr[m] = *(const half4*)(xnh + off);
        L0r[m] = *(const half4*)(lamh + qoff);
        L1r[m] = *(const half4*)(lamh + qoff + VOL);
        L2r[m] = *(const half4*)(lamh + qoff + 2 * VOL);
    }

    // ring lambdas (level-1 backward q rings at lx=-1 / ly=-1)
    half4 LRr;
    if (tid < 64) {
        int rly = tid >> 2;
        LRr = *(const half4*)(lamh + qbase +
              (wrap(X0 - 4) * YDIM + wrap(Y0 - 3 + rly)) * TDIM + t0);
    } else if (tid < 128) {
        int rlx = (tid - 64) >> 2;
        LRr = *(const half4*)(lamh + qbase + VOL +
              (wrap(X0 - 3 + rlx) * YDIM + wrap(Y0 - 4)) * TDIM + t0);
    }

    __syncthreads();

    // slot xbar from the staged LDS copy (same cvt value as global)
    #pragma unroll
    for (int m = 0; m < 2; ++m) {
        int line = 128 * m + (tid >> 2);
        int lx = line >> 4, ly = line & 15;
        ld4(xbS + ((lx + 1) * R0S + (ly + 1)) * TDIM + t0, xb[m]);
    }

    // ---- level loop: k = 1..4 ----
    #pragma unroll
    for (int k = 1; k <= 4; ++k) {
        const int lo = k - 1, hi = 17 - k;

        // ===== phase B: update p, q (own); write q0,q1 to LDS =====
        if (k == 1) {
            // level-1 backward rings (outside R1): q at lx=-1 / ly=-1
            if (tid < 64) {
                int rly = tid >> 2;
                float qr[4], xbc[4], xpx[4];
                ld4(q0S + (0 * R1S + rly) * TDIM + t0, qr);
                ld4(xbS + (0 * R0S + (rly + 1)) * TDIM + t0, xbc);
                ld4(xbS + (1 * R0S + (rly + 1)) * TDIM + t0, xpx);
                #pragma unroll
                for (int j = 0; j < 4; ++j)
                    qr[j] = clampl(qr[j] + sigma * (xpx[j] - xbc[j]), (float)LRr[j]);
                st4(q0S + (0 * R1S + rly) * TDIM + t0, qr);
            } else if (tid < 128) {
                int rlx = (tid - 64) >> 2;
                float qr[4], xbc[4], xpy[4];
                ld4(q1S + (rlx * 17 + 0) * TDIM + t0, qr);
                ld4(xbS + ((rlx + 1) * R0S + 0) * TDIM + t0, xbc);
                ld4(xbS + ((rlx + 1) * R0S + 1) * TDIM + t0, xpy);
                #pragma unroll
                for (int j = 0; j < 4; ++j)
                    qr[j] = clampl(qr[j] + sigma * (xpy[j] - xbc[j]), (float)LRr[j]);
                st4(q1S + (rlx * 17 + 0) * TDIM + t0, qr);
            }
        }

        #pragma unroll
        for (int m = 0; m < 2; ++m) {
            int line = 128 * m + (tid >> 2);
            int lx = line >> 4, ly = line & 15;
            bool inX = (lx >= lo && lx < hi), inY = (ly >= lo && ly < hi);
            bool aq0 = inY && (lx >= lo - 1) && (lx < hi);
            bool aq1 = inX && (ly >= lo - 1) && (ly < hi);
            bool ax  = inX && inY;

            if (k == 1) {   // own q0,q1 from staged LDS (== global cvt)
                ld4(q0S + ((lx + 1) * R1S + ly) * TDIM + t0, q0[m]);
                ld4(q1S + (lx * 17 + (ly + 1)) * TDIM + t0, q1[m]);
            }
            if (aq0) {
                float xpx[4];
                ld4(xbS + ((lx + 2) * R0S + (ly + 1)) * TDIM + t0, xpx);
                #pragma unroll
                for (int j = 0; j < 4; ++j)
                    q0[m][j] = clampl(q0[m][j] + sigma * (xpx[j] - xb[m][j]),
                                      (float)L0r[m][j]);
                st4(q0S + ((lx + 1) * R1S + ly) * TDIM + t0, q0[m]);
            }
            if (aq1) {
                float xpy[4];
                ld4(xbS + ((lx + 1) * R0S + (ly + 2)) * TDIM + t0, xpy);
                #pragma unroll
                for (int j = 0; j < 4; ++j)
                    q1[m][j] = clampl(q1[m][j] + sigma * (xpy[j] - xb[m][j]),
                                      (float)L1r[m][j]);
                st4(q1S + (lx * 17 + (ly + 1)) * TDIM + t0, q1[m]);
            }
            if (ax) {
                float xb_tp = __shfl(xb[m][0], upSrc, 64);   // xbar at t0+4
                #pragma unroll
                for (int j = 0; j < 4; ++j) {
                    float gt = ((j < 3) ? xb[m][j + 1] : xb_tp) - xb[m][j];
                    q2[m][j] = clampl(q2[m][j] + sigma * gt, (float)L2r[m][j]);
                    p[m][j]  = (p[m][j] + sigma * (xb[m][j] - (float)XNr[m][j]))
                               * inv1ps;
                }
            }
        }
        __syncthreads();

        // ===== phase C: read backward q (new) from LDS; update x, xbar =====
        #pragma unroll
        for (int m = 0; m < 2; ++m) {
            int line = 128 * m + (tid >> 2);
            int lx = line >> 4, ly = line & 15;
            bool ax = (lx >= lo && lx < hi && ly >= lo && ly < hi);
            if (ax) {
                float q0b[4], q1b[4];
                ld4(q0S + (lx * R1S + ly) * TDIM + t0, q0b);       // (lx-1,ly)
                ld4(q1S + (lx * 17 + ly) * TDIM + t0, q1b);        // (lx,ly-1)
                float q2tm = __shfl(q2[m][3], dnSrc, 64);          // new, t0-1
                #pragma unroll
                for (int j = 0; j < 4; ++j) {
                    float q2p = (j == 0) ? q2tm : q2[m][j - 1];
                    float div = (q0b[j] - q0[m][j]) + (q1b[j] - q1[m][j])
                              + (q2p - q2[m][j]);
                    float xnew = xv[m][j] - tau * (p[m][j] + div);
                    xb[m][j] = xnew + theta * (xnew - xv[m][j]);
                    xv[m][j] = xnew;
                }
                if (k < 4)
                    st4(xbS + ((lx + 1) * R0S + (ly + 1)) * TDIM + t0, xb[m]);
            }
        }
        if (k < 4) __syncthreads();
    }

    // ---- output: center 10x10 lines ----
    #pragma unroll
    for (int m = 0; m < 2; ++m) {
        int line = 128 * m + (tid >> 2);
        int lx = line >> 4, ly = line & 15;
        if (lx >= 3 && lx < 13 && ly >= 3 && ly < 13) {
            int gx = X0 + lx - 3, gy = Y0 + ly - 3;
            int off  = xbase + (gx * YDIM + gy) * TDIM + t0;
            int qoff = qbase + (gx * YDIM + gy) * TDIM + t0;
            st4(pOut + off, p[m]);
            st4(xOut + off, xv[m]);
            half4 h;
            h.x = (hreal)xb[m][0]; h.y = (hreal)xb[m][1];
            h.z = (hreal)xb[m][2]; h.w = (hreal)xb[m][3];
            *(half4*)(xbOut + off) = h;
            h.x = (hreal)q0[m][0]; h.y = (hreal)q0[m][1];
            h.z = (hreal)q0[m][2]; h.w = (hreal)q0[m][3];
            *(half4*)(qOut + qoff) = h;
            h.x = (hreal)q1[m][0]; h.y = (hreal)q1[m][1];
            h.z = (hreal)q1[m][2]; h.w = (hreal)q1[m][3];
            *(half4*)(qOut + qoff + VOL) = h;
            h.x = (hreal)q2[m][0]; h.y = (hreal)q2[m][1];
            h.z = (hreal)q2[m][2]; h.w = (hreal)q2[m][3];
            *(half4*)(qOut + qoff + 2 * VOL) = h;
        }
    }
}

extern "C" void kernel_launch(void* const* d_in, const int* in_sizes, int n_in,
                              void* d_out, int out_size, void* d_ws, size_t ws_size,
                              hipStream_t stream) {
    const float* x   = (const float*)d_in[0];
    const float* lam = (const float*)d_in[1];
    float* out = (float*)d_out;
    float* ws  = (float*)d_ws;

    // ws: [pA|pB|xB] fp32 (3*NX floats) then fp16 region (12*NX halves)
    float* pA  = ws;
    float* pB  = ws + (size_t)NX;
    float* xBb = ws + (size_t)2 * NX;
    float* xAb = out;   // 12 launches: final (odd j) writes A family -> d_out
    hreal* hb  = (hreal*)(ws + (size_t)3 * NX);
    hreal* xbAh = hb;
    hreal* xbBh = hb + (size_t)NX;
    hreal* qAh  = hb + (size_t)2 * NX;
    hreal* qBh  = hb + (size_t)5 * NX;
    hreal* lamh = hb + (size_t)8 * NX;
    hreal* xnh  = hb + (size_t)11 * NX;

    const double s10 = 1.0 / (1.0 + exp(-10.0));
    const double L   = sqrt(13.0);
    float sigma  = (float)(s10 / L);
    float tau    = sigma;
    float theta  = (float)s10;
    float inv1ps = (float)(1.0 / (1.0 + s10 / L));

    init_kernel<<<(3 * NX + 255) / 256, 256, 0, stream>>>(
        x, lam, pA, xAb, xbAh, qAh, lamh, xnh);

    for (int j = 0; j < T_ITERS / 4; ++j) {   // 12 launches
        const bool e = (j & 1) == 0;
        pd_step4<<<NBLK, NTHR, 0, stream>>>(
            xnh, lamh,
            e ? pA : pB,   e ? pB : pA,
            e ? xAb : xBb, e ? xBb : xAb,
            e ? xbAh : xbBh, e ? xbBh : xbAh,
            e ? qAh : qBh,  e ? qBh : qAh,
            sigma, inv1ps, tau, theta);
    }
}